// Round 1
// baseline (9117.221 us; speedup 1.0000x reference)
//
#include <hip/hip_runtime.h>

#define GEMM_BLOCKS 512
#define GNUM 4096   // num graphs (fixed in reference)

// ---------------------------------------------------------------- init
// agg = (1+eps)*x, elementwise float4
__global__ __launch_bounds__(256) void init_agg_kernel(
    const float* __restrict__ x, const float* __restrict__ epsp,
    float* __restrict__ agg, int total4)
{
    int i = blockIdx.x * 256 + threadIdx.x;
    if (i >= total4) return;
    float s = 1.0f + epsp[0];
    float4 v = reinterpret_cast<const float4*>(x)[i];
    v.x *= s; v.y *= s; v.z *= s; v.w *= s;
    reinterpret_cast<float4*>(agg)[i] = v;
}

// ---------------------------------------------------------------- edge
// For each edge: e = ea@ew + eb  (16 x C), msg = relu(x[src] + e),
// agg[dst] += msg (fp32 atomics). ew fragment held in registers
// (thread owns 4 channels), ea tile staged in LDS with padded rows.
template<int C>
__global__ __launch_bounds__(256) void edge_kernel(
    const float* __restrict__ ea, const int* __restrict__ srcv,
    const int* __restrict__ dstv, const float* __restrict__ ew,
    const float* __restrict__ ebias, const float* __restrict__ x,
    float* __restrict__ agg, int E)
{
    constexpr int CT = C / 4;        // threads per edge (channels/4)
    constexpr int EP = 256 / CT;     // edges in flight per block
    __shared__ float ea_s[32][20];   // pad 16->20 floats: 80B rows, 16B aligned
    __shared__ int src_s[32];
    __shared__ int dst_s[32];
    const int tid = threadIdx.x;
    const int c0 = (tid % CT) * 4;
    const int eo = tid / CT;

    // ew fragment: [16][4] for this thread's channels (registers)
    float ewr[16][4];
    #pragma unroll
    for (int k = 0; k < 16; k++) {
        float4 w = *reinterpret_cast<const float4*>(&ew[k * C + c0]);
        ewr[k][0] = w.x; ewr[k][1] = w.y; ewr[k][2] = w.z; ewr[k][3] = w.w;
    }
    float4 ebr = *reinterpret_cast<const float4*>(&ebias[c0]);

    for (int t0 = blockIdx.x * 32; t0 < E; t0 += gridDim.x * 32) {
        __syncthreads();
        #pragma unroll
        for (int i = 0; i < 2; i++) {            // stage 32 edges x 16 attrs
            int idx = i * 256 + tid;
            int e = t0 + (idx >> 4);
            ea_s[idx >> 4][idx & 15] = (e < E) ? ea[e * 16 + (idx & 15)] : 0.f;
        }
        if (tid < 32)              { int e = t0 + tid;      src_s[tid]      = (e < E) ? srcv[e] : 0; }
        if (tid >= 64 && tid < 96) { int e = t0 + tid - 64; dst_s[tid - 64] = (e < E) ? dstv[e] : 0; }
        __syncthreads();
        #pragma unroll
        for (int eiter = 0; eiter < 32 / EP; eiter++) {
            int e = eo + eiter * EP;
            if (t0 + e >= E) continue;
            float acc[4] = {ebr.x, ebr.y, ebr.z, ebr.w};
            #pragma unroll
            for (int k4 = 0; k4 < 4; k4++) {
                float4 av = *reinterpret_cast<const float4*>(&ea_s[e][k4 * 4]);
                #pragma unroll
                for (int j = 0; j < 4; j++) {
                    acc[j] = fmaf(av.x, ewr[k4*4 + 0][j], acc[j]);
                    acc[j] = fmaf(av.y, ewr[k4*4 + 1][j], acc[j]);
                    acc[j] = fmaf(av.z, ewr[k4*4 + 2][j], acc[j]);
                    acc[j] = fmaf(av.w, ewr[k4*4 + 3][j], acc[j]);
                }
            }
            float4 xv = *reinterpret_cast<const float4*>(&x[(size_t)src_s[e] * C + c0]);
            float m0 = fmaxf(xv.x + acc[0], 0.f);
            float m1 = fmaxf(xv.y + acc[1], 0.f);
            float m2 = fmaxf(xv.z + acc[2], 0.f);
            float m3 = fmaxf(xv.w + acc[3], 0.f);
            float* ap = &agg[(size_t)dst_s[e] * C + c0];
            atomicAdd(ap + 0, m0);
            atomicAdd(ap + 1, m1);
            atomicAdd(ap + 2, m2);
            atomicAdd(ap + 3, m3);
        }
    }
}

// ---------------------------------------------------------------- GEMM + BN stats
// out[N,128] = f(A)[N,K] @ W[K,128] + bias, where f = identity (k1) or
// lrelu(bn(.)) using scale/shift ss[2K] (k2). Also emits per-block column
// sum / sumsq partials of out for the NEXT batchnorm.
// In-place safe (out==A): each block fully reads its 64-row tile before writing.
template<int K, bool BN_IN>
__global__ __launch_bounds__(256) void gemm_bn_kernel(
    const float* __restrict__ A, const float* __restrict__ ss,
    const float* __restrict__ W, const float* __restrict__ bias,
    float* __restrict__ out, float* __restrict__ partials, int N)
{
    __shared__ float w_s[K * 128];
    __shared__ float red_s[16 * 128];
    __shared__ float scale_s[K];
    __shared__ float shift_s[K];
    const int tid = threadIdx.x;
    for (int i = tid; i < K * 128; i += 256) w_s[i] = W[i];
    if (BN_IN) {
        for (int i = tid; i < K; i += 256) { scale_s[i] = ss[i]; shift_s[i] = ss[K + i]; }
    }
    __syncthreads();
    const int ri = tid >> 4;    // 0..15 -> rows ri*4 .. ri*4+3
    const int ci = tid & 15;    // 0..15 -> cols ci*8 .. ci*8+7
    const int c0 = ci * 8;
    float bj[8];
    #pragma unroll
    for (int j = 0; j < 8; j++) bj[j] = bias[c0 + j];
    float bsum[8], bsq[8];
    #pragma unroll
    for (int j = 0; j < 8; j++) { bsum[j] = 0.f; bsq[j] = 0.f; }

    for (int row0 = blockIdx.x * 64; row0 < N; row0 += gridDim.x * 64) {
        const int r0 = row0 + ri * 4;
        float acc[4][8];
        #pragma unroll
        for (int i = 0; i < 4; i++)
            #pragma unroll
            for (int j = 0; j < 8; j++) acc[i][j] = 0.f;
        for (int kb = 0; kb < K; kb += 8) {
            float a[4][8];
            #pragma unroll
            for (int i = 0; i < 4; i++) {
                int r = r0 + i;
                if (r < N) {
                    float4 u0 = *reinterpret_cast<const float4*>(&A[(size_t)r * K + kb]);
                    float4 u1 = *reinterpret_cast<const float4*>(&A[(size_t)r * K + kb + 4]);
                    a[i][0]=u0.x; a[i][1]=u0.y; a[i][2]=u0.z; a[i][3]=u0.w;
                    a[i][4]=u1.x; a[i][5]=u1.y; a[i][6]=u1.z; a[i][7]=u1.w;
                } else {
                    #pragma unroll
                    for (int kk = 0; kk < 8; kk++) a[i][kk] = 0.f;
                }
                if (BN_IN) {
                    #pragma unroll
                    for (int kk = 0; kk < 8; kk++) {
                        float v = fmaf(a[i][kk], scale_s[kb + kk], shift_s[kb + kk]);
                        a[i][kk] = (v > 0.f) ? v : 0.01f * v;
                    }
                }
            }
            #pragma unroll
            for (int kk = 0; kk < 8; kk++) {
                float4 w0 = *reinterpret_cast<const float4*>(&w_s[(kb + kk) * 128 + c0]);
                float4 w1 = *reinterpret_cast<const float4*>(&w_s[(kb + kk) * 128 + c0 + 4]);
                float w[8] = {w0.x, w0.y, w0.z, w0.w, w1.x, w1.y, w1.z, w1.w};
                #pragma unroll
                for (int i = 0; i < 4; i++)
                    #pragma unroll
                    for (int j = 0; j < 8; j++) acc[i][j] = fmaf(a[i][kk], w[j], acc[i][j]);
            }
        }
        #pragma unroll
        for (int i = 0; i < 4; i++) {
            int r = r0 + i;
            if (r < N) {
                float v[8];
                #pragma unroll
                for (int j = 0; j < 8; j++) v[j] = acc[i][j] + bj[j];
                float4 o0 = {v[0], v[1], v[2], v[3]};
                float4 o1 = {v[4], v[5], v[6], v[7]};
                *reinterpret_cast<float4*>(&out[(size_t)r * 128 + c0]) = o0;
                *reinterpret_cast<float4*>(&out[(size_t)r * 128 + c0 + 4]) = o1;
                #pragma unroll
                for (int j = 0; j < 8; j++) { bsum[j] += v[j]; bsq[j] += v[j] * v[j]; }
            }
        }
    }
    // block-level column reduction -> partials[block][0:128]=sum, [128:256]=sumsq
    __syncthreads();
    #pragma unroll
    for (int j = 0; j < 8; j++) red_s[ri * 128 + c0 + j] = bsum[j];
    __syncthreads();
    if (tid < 128) {
        float s = 0.f;
        #pragma unroll
        for (int i = 0; i < 16; i++) s += red_s[i * 128 + tid];
        partials[blockIdx.x * 256 + tid] = s;
    }
    __syncthreads();
    #pragma unroll
    for (int j = 0; j < 8; j++) red_s[ri * 128 + c0 + j] = bsq[j];
    __syncthreads();
    if (tid < 128) {
        float s = 0.f;
        #pragma unroll
        for (int i = 0; i < 16; i++) s += red_s[i * 128 + tid];
        partials[blockIdx.x * 256 + 128 + tid] = s;
    }
}

// ---------------------------------------------------------------- BN stats reduce
// scale = g * rsqrt(var + eps); shift = beta - mean*scale  -> ss[256]
__global__ __launch_bounds__(128) void reduce_stats_kernel(
    const float* __restrict__ partials, int NB, float invN,
    const float* __restrict__ g, const float* __restrict__ be,
    float* __restrict__ ss)
{
    int c = threadIdx.x;
    float s = 0.f, q = 0.f;
    for (int b = 0; b < NB; b++) {
        s += partials[b * 256 + c];
        q += partials[b * 256 + 128 + c];
    }
    float mean = s * invN;
    float var = fmaxf(q * invN - mean * mean, 0.f);
    float inv = rsqrtf(var + 1e-5f);
    float scale = g[c] * inv;
    ss[c] = scale;
    ss[128 + c] = be[c] - mean * scale;
}

// ---------------------------------------------------------------- bn+lrelu elementwise
__global__ __launch_bounds__(256) void bn_lrelu_kernel(
    const float* __restrict__ U, const float* __restrict__ ss,
    float* __restrict__ xo, int total4)
{
    int i = blockIdx.x * 256 + threadIdx.x;
    if (i >= total4) return;
    int cq = (i & 31) * 4;   // row is 128 floats = 32 float4s
    float4 v = reinterpret_cast<const float4*>(U)[i];
    float s0 = ss[cq], s1 = ss[cq + 1], s2 = ss[cq + 2], s3 = ss[cq + 3];
    float h0 = ss[128 + cq], h1 = ss[129 + cq], h2 = ss[130 + cq], h3 = ss[131 + cq];
    v.x = fmaf(v.x, s0, h0); v.x = (v.x > 0.f) ? v.x : 0.01f * v.x;
    v.y = fmaf(v.y, s1, h1); v.y = (v.y > 0.f) ? v.y : 0.01f * v.y;
    v.z = fmaf(v.z, s2, h2); v.z = (v.z > 0.f) ? v.z : 0.01f * v.z;
    v.w = fmaf(v.w, s3, h3); v.w = (v.w > 0.f) ? v.w : 0.01f * v.w;
    reinterpret_cast<float4*>(xo)[i] = v;
}

// ---------------------------------------------------------------- global add pool
__global__ __launch_bounds__(256) void pool_kernel(
    const float* __restrict__ x3, const int* __restrict__ batch,
    float* __restrict__ pool, int N)
{
    int idx = blockIdx.x * 256 + threadIdx.x;
    if (idx >= N * 128) return;
    int n = idx >> 7, c = idx & 127;
    atomicAdd(&pool[(size_t)batch[n] * 128 + c], x3[idx]);
}

// ---------------------------------------------------------------- final: cat -> linear -> softmax
// one wave per node; lane l covers channels l and l+64 of both x and pool.
__global__ __launch_bounds__(256) void final_kernel(
    const float* __restrict__ x3, const float* __restrict__ pool,
    const int* __restrict__ batch, const float* __restrict__ wf,
    const float* __restrict__ bf, float* __restrict__ out, int N)
{
    __shared__ float wf_s[512];   // wf[256][2]
    int tid = threadIdx.x;
    for (int i = tid; i < 512; i += 256) wf_s[i] = wf[i];
    __syncthreads();
    int wid = tid >> 6, lane = tid & 63;
    int n = blockIdx.x * 4 + wid;
    if (n >= N) return;
    int b = batch[n];
    float v0 = x3[(size_t)n * 128 + lane];
    float v1 = x3[(size_t)n * 128 + 64 + lane];
    float p0 = pool[(size_t)b * 128 + lane];
    float p1 = pool[(size_t)b * 128 + 64 + lane];
    float a0 = v0 * wf_s[lane * 2]       + v1 * wf_s[(64 + lane) * 2]
             + p0 * wf_s[(128 + lane) * 2] + p1 * wf_s[(192 + lane) * 2];
    float a1 = v0 * wf_s[lane * 2 + 1]       + v1 * wf_s[(64 + lane) * 2 + 1]
             + p0 * wf_s[(128 + lane) * 2 + 1] + p1 * wf_s[(192 + lane) * 2 + 1];
    #pragma unroll
    for (int off = 32; off >= 1; off >>= 1) {
        a0 += __shfl_down(a0, off);
        a1 += __shfl_down(a1, off);
    }
    if (lane == 0) {
        a0 += bf[0]; a1 += bf[1];
        float mx = fmaxf(a0, a1);
        float e0 = __expf(a0 - mx), e1 = __expf(a1 - mx);
        float inv = 1.f / (e0 + e1);
        out[(size_t)n * 2]     = e0 * inv;
        out[(size_t)n * 2 + 1] = e1 * inv;
    }
}

// ---------------------------------------------------------------- launch
extern "C" void kernel_launch(void* const* d_in, const int* in_sizes, int n_in,
                              void* d_out, int out_size, void* d_ws, size_t ws_size,
                              hipStream_t stream)
{
    const float* x0    = (const float*)d_in[0];
    const int*   ei    = (const int*)d_in[1];
    const float* ea    = (const float*)d_in[2];
    const int*   batch = (const int*)d_in[3];
    const int E = in_sizes[1] / 2;
    const int N = in_sizes[3];
    const int* srcv = ei;
    const int* dstv = ei + E;
    const float* wf = (const float*)d_in[37];
    const float* bf = (const float*)d_in[38];
    float* ws = (float*)d_ws;

    // workspace layout (2 big buffers; k2 runs in-place so T==U)
    float* buf[2] = { ws, ws + (size_t)N * 128 };
    float* poolb  = ws + (size_t)2 * N * 128;
    float* part   = poolb + (size_t)GNUM * 128;
    float* ss1    = part + (size_t)GEMM_BLOCKS * 256;
    float* ss2    = ss1 + 256;
    float* out    = (float*)d_out;
    const float invN = 1.0f / (float)N;

    int eblocks = (E + 31) / 32; if (eblocks > 2048) eblocks = 2048;

    for (int l = 0; l < 3; l++) {
        const int C = (l == 0) ? 32 : 128;
        const float* xin = (l == 0) ? x0 : buf[(l + 1) & 1];
        float* agg  = buf[l & 1];
        float* T    = buf[(l + 1) & 1];   // k2 in-place: U aliases T
        float* xout = buf[l & 1];
        int bidx = 4 + l * 11;
        const float* epsp = (const float*)d_in[bidx + 0];
        const float* ew   = (const float*)d_in[bidx + 1];
        const float* eb   = (const float*)d_in[bidx + 2];
        const float* w1   = (const float*)d_in[bidx + 3];
        const float* b1   = (const float*)d_in[bidx + 4];
        const float* g1   = (const float*)d_in[bidx + 5];
        const float* be1  = (const float*)d_in[bidx + 6];
        const float* w2   = (const float*)d_in[bidx + 7];
        const float* b2   = (const float*)d_in[bidx + 8];
        const float* g2   = (const float*)d_in[bidx + 9];
        const float* be2  = (const float*)d_in[bidx + 10];

        int total4 = N * C / 4;
        init_agg_kernel<<<(total4 + 255) / 256, 256, 0, stream>>>(xin, epsp, agg, total4);
        if (C == 32)
            edge_kernel<32><<<eblocks, 256, 0, stream>>>(ea, srcv, dstv, ew, eb, xin, agg, E);
        else
            edge_kernel<128><<<eblocks, 256, 0, stream>>>(ea, srcv, dstv, ew, eb, xin, agg, E);
        if (C == 32)
            gemm_bn_kernel<32, false><<<GEMM_BLOCKS, 256, 0, stream>>>(agg, nullptr, w1, b1, T, part, N);
        else
            gemm_bn_kernel<128, false><<<GEMM_BLOCKS, 256, 0, stream>>>(agg, nullptr, w1, b1, T, part, N);
        reduce_stats_kernel<<<1, 128, 0, stream>>>(part, GEMM_BLOCKS, invN, g1, be1, ss1);
        gemm_bn_kernel<128, true><<<GEMM_BLOCKS, 256, 0, stream>>>(T, ss1, w2, b2, T, part, N);
        reduce_stats_kernel<<<1, 128, 0, stream>>>(part, GEMM_BLOCKS, invN, g2, be2, ss2);
        int t4 = N * 128 / 4;
        bn_lrelu_kernel<<<(t4 + 255) / 256, 256, 0, stream>>>(T, ss2, xout, t4);
    }
    hipMemsetAsync(poolb, 0, (size_t)GNUM * 128 * 4, stream);
    pool_kernel<<<(N * 128 + 255) / 256, 256, 0, stream>>>(buf[0], batch, poolb, N);
    final_kernel<<<(N + 3) / 4, 256, 0, stream>>>(buf[0], poolb, batch, wf, bf, out, N);
}

// Round 2
// 2502.902 us; speedup vs baseline: 3.6427x; 3.6427x over previous
//
#include <hip/hip_runtime.h>

#define GEMM_BLOCKS 512
#define GNUM 4096   // num graphs (fixed in reference)

// ================================================================ CSR build
__global__ __launch_bounds__(256) void hist_kernel(
    const int* __restrict__ dstv, int* __restrict__ cnt, int E)
{
    int i = blockIdx.x * 256 + threadIdx.x;
    if (i < E) atomicAdd(&cnt[dstv[i] + 1], 1);
}

// inclusive scan of data[0..n) in-place, chunk=1024/block; bsum[b]=chunk total
__global__ __launch_bounds__(256) void scan_block_kernel(
    int* __restrict__ data, int* __restrict__ bsum, int n)
{
    __shared__ int s[256];
    int tid = threadIdx.x;
    int base = blockIdx.x * 1024 + tid * 4;
    int v[4]; int run = 0;
    #pragma unroll
    for (int i = 0; i < 4; i++) {
        int x = (base + i < n) ? data[base + i] : 0;
        run += x; v[i] = run;
    }
    s[tid] = run; __syncthreads();
    for (int off = 1; off < 256; off <<= 1) {
        int t = (tid >= off) ? s[tid - off] : 0;
        __syncthreads();
        s[tid] += t;
        __syncthreads();
    }
    int excl = s[tid] - run;
    #pragma unroll
    for (int i = 0; i < 4; i++)
        if (base + i < n) data[base + i] = v[i] + excl;
    if (tid == 255) bsum[blockIdx.x] = s[255];
}

// exclusive scan of bsum[0..nb), nb <= 128
__global__ __launch_bounds__(128) void scan_carry_kernel(int* __restrict__ bsum, int nb)
{
    __shared__ int s[128];
    int tid = threadIdx.x;
    int orig = (tid < nb) ? bsum[tid] : 0;
    s[tid] = orig; __syncthreads();
    for (int off = 1; off < 128; off <<= 1) {
        int t = (tid >= off) ? s[tid - off] : 0;
        __syncthreads();
        s[tid] += t;
        __syncthreads();
    }
    if (tid < nb) bsum[tid] = s[tid] - orig;
}

__global__ __launch_bounds__(256) void scan_add_kernel(
    int* __restrict__ data, const int* __restrict__ bsum,
    int* __restrict__ cursor, int n, int N)
{
    int i = blockIdx.x * 256 + threadIdx.x;
    if (i < n) {
        int v = data[i] + bsum[i >> 10];
        data[i] = v;
        if (i < N) cursor[i] = v;
    }
}

__global__ __launch_bounds__(256) void scatter_kernel(
    const int* __restrict__ dstv, int* __restrict__ cursor,
    int* __restrict__ perm, int E)
{
    int i = blockIdx.x * 256 + threadIdx.x;
    if (i < E) {
        int p = atomicAdd(&cursor[dstv[i]], 1);
        perm[p] = i;
    }
}

// ================================================================ edge gather
// agg[n] = (1+eps)*x[n] + sum_{e: dst(e)=n} relu(x[src(e)] + ea[e]@ew + eb)
// One wave per node; edge indices wave-uniform -> scalar loads; no atomics.

// C = 128: lane owns channels {2*lane, 2*lane+1}; 2-edge unroll for MLP.
__global__ __launch_bounds__(256) void gather_kernel128(
    const float* __restrict__ ea, const int* __restrict__ srcv,
    const int* __restrict__ perm, const int* __restrict__ off,
    const float* __restrict__ ew, const float* __restrict__ ebias,
    const float* __restrict__ epsp, const float* __restrict__ x,
    float* __restrict__ agg, int N)
{
    int lane = threadIdx.x & 63;
    int n = __builtin_amdgcn_readfirstlane((int)((blockIdx.x * 256 + threadIdx.x) >> 6));
    if (n >= N) return;
    const int c0 = lane * 2;
    float ew0[16], ew1[16];
    #pragma unroll
    for (int k = 0; k < 16; k++) {
        float2 w = *reinterpret_cast<const float2*>(&ew[k * 128 + c0]);
        ew0[k] = w.x; ew1[k] = w.y;
    }
    const float eb0 = ebias[c0], eb1 = ebias[c0 + 1];
    float acc0 = 0.f, acc1 = 0.f;
    int p = off[n];
    const int end = off[n + 1];
    for (; p + 2 <= end; p += 2) {
        int e0 = perm[p], e1 = perm[p + 1];
        int s0 = srcv[e0], s1 = srcv[e1];
        const float4* ap0 = reinterpret_cast<const float4*>(ea + (size_t)e0 * 16);
        const float4* ap1 = reinterpret_cast<const float4*>(ea + (size_t)e1 * 16);
        float av[16], bv[16];
        #pragma unroll
        for (int q = 0; q < 4; q++) {
            float4 t = ap0[q]; av[4*q]=t.x; av[4*q+1]=t.y; av[4*q+2]=t.z; av[4*q+3]=t.w;
            float4 u = ap1[q]; bv[4*q]=u.x; bv[4*q+1]=u.y; bv[4*q+2]=u.z; bv[4*q+3]=u.w;
        }
        float2 xv0 = *reinterpret_cast<const float2*>(&x[(size_t)s0 * 128 + c0]);
        float2 xv1 = *reinterpret_cast<const float2*>(&x[(size_t)s1 * 128 + c0]);
        float u0 = eb0, u1 = eb1, w0 = eb0, w1 = eb1;
        #pragma unroll
        for (int k = 0; k < 16; k++) {
            u0 = fmaf(av[k], ew0[k], u0);
            u1 = fmaf(av[k], ew1[k], u1);
            w0 = fmaf(bv[k], ew0[k], w0);
            w1 = fmaf(bv[k], ew1[k], w1);
        }
        acc0 += fmaxf(xv0.x + u0, 0.f) + fmaxf(xv1.x + w0, 0.f);
        acc1 += fmaxf(xv0.y + u1, 0.f) + fmaxf(xv1.y + w1, 0.f);
    }
    if (p < end) {
        int e0 = perm[p];
        int s0 = srcv[e0];
        const float4* ap0 = reinterpret_cast<const float4*>(ea + (size_t)e0 * 16);
        float av[16];
        #pragma unroll
        for (int q = 0; q < 4; q++) {
            float4 t = ap0[q]; av[4*q]=t.x; av[4*q+1]=t.y; av[4*q+2]=t.z; av[4*q+3]=t.w;
        }
        float2 xv0 = *reinterpret_cast<const float2*>(&x[(size_t)s0 * 128 + c0]);
        float u0 = eb0, u1 = eb1;
        #pragma unroll
        for (int k = 0; k < 16; k++) {
            u0 = fmaf(av[k], ew0[k], u0);
            u1 = fmaf(av[k], ew1[k], u1);
        }
        acc0 += fmaxf(xv0.x + u0, 0.f);
        acc1 += fmaxf(xv0.y + u1, 0.f);
    }
    float2 xn = *reinterpret_cast<const float2*>(&x[(size_t)n * 128 + c0]);
    float s = 1.f + epsp[0];
    float2 o;
    o.x = fmaf(xn.x, s, acc0);
    o.y = fmaf(xn.y, s, acc1);
    *reinterpret_cast<float2*>(&agg[(size_t)n * 128 + c0]) = o;
}

// C = 32: half-wave per edge (2 edges in flight), lane owns channel lane&31.
__global__ __launch_bounds__(256) void gather_kernel32(
    const float* __restrict__ ea, const int* __restrict__ srcv,
    const int* __restrict__ perm, const int* __restrict__ off,
    const float* __restrict__ ew, const float* __restrict__ ebias,
    const float* __restrict__ epsp, const float* __restrict__ x,
    float* __restrict__ agg, int N)
{
    int lane = threadIdx.x & 63;
    int n = __builtin_amdgcn_readfirstlane((int)((blockIdx.x * 256 + threadIdx.x) >> 6));
    if (n >= N) return;
    const int h = lane >> 5;
    const int c = lane & 31;
    float ewr[16];
    #pragma unroll
    for (int k = 0; k < 16; k++) ewr[k] = ew[k * 32 + c];
    const float ebr = ebias[c];
    float acc = 0.f;
    const int p0 = off[n], end = off[n + 1];
    for (int p = p0; p < end; p += 2) {
        int pp = p + h;
        bool valid = (pp < end);
        int e = perm[valid ? pp : p];
        int sn = srcv[e];
        const float4* ap = reinterpret_cast<const float4*>(ea + (size_t)e * 16);
        float av[16];
        #pragma unroll
        for (int q = 0; q < 4; q++) {
            float4 t = ap[q]; av[4*q]=t.x; av[4*q+1]=t.y; av[4*q+2]=t.z; av[4*q+3]=t.w;
        }
        float xv = x[(size_t)sn * 32 + c];
        float u = ebr;
        #pragma unroll
        for (int k = 0; k < 16; k++) u = fmaf(av[k], ewr[k], u);
        float m = fmaxf(xv + u, 0.f);
        acc += valid ? m : 0.f;
    }
    acc += __shfl_xor(acc, 32);
    if (lane < 32) {
        float s = 1.f + epsp[0];
        agg[(size_t)n * 32 + c] = fmaf(x[(size_t)n * 32 + c], s, acc);
    }
}

// ================================================================ GEMM + BN stats
// out[N,128] = f(A)[N,K] @ W[K,128] + bias; f = identity or lrelu(bn(.)).
// Emits per-block column sum/sumsq partials. In-place safe (out==A).
template<int K, bool BN_IN>
__global__ __launch_bounds__(256) void gemm_bn_kernel(
    const float* __restrict__ A, const float* __restrict__ ss,
    const float* __restrict__ W, const float* __restrict__ bias,
    float* __restrict__ out, float* __restrict__ partials, int N)
{
    __shared__ float w_s[K * 128];
    __shared__ float red_s[16 * 128];
    __shared__ float scale_s[K];
    __shared__ float shift_s[K];
    const int tid = threadIdx.x;
    for (int i = tid; i < K * 128; i += 256) w_s[i] = W[i];
    if (BN_IN) {
        for (int i = tid; i < K; i += 256) { scale_s[i] = ss[i]; shift_s[i] = ss[K + i]; }
    }
    __syncthreads();
    const int ri = tid >> 4;
    const int ci = tid & 15;
    const int c0 = ci * 8;
    float bj[8];
    #pragma unroll
    for (int j = 0; j < 8; j++) bj[j] = bias[c0 + j];
    float bsum[8], bsq[8];
    #pragma unroll
    for (int j = 0; j < 8; j++) { bsum[j] = 0.f; bsq[j] = 0.f; }

    for (int row0 = blockIdx.x * 64; row0 < N; row0 += gridDim.x * 64) {
        const int r0 = row0 + ri * 4;
        float acc[4][8];
        #pragma unroll
        for (int i = 0; i < 4; i++)
            #pragma unroll
            for (int j = 0; j < 8; j++) acc[i][j] = 0.f;
        for (int kb = 0; kb < K; kb += 8) {
            float a[4][8];
            #pragma unroll
            for (int i = 0; i < 4; i++) {
                int r = r0 + i;
                if (r < N) {
                    float4 u0 = *reinterpret_cast<const float4*>(&A[(size_t)r * K + kb]);
                    float4 u1 = *reinterpret_cast<const float4*>(&A[(size_t)r * K + kb + 4]);
                    a[i][0]=u0.x; a[i][1]=u0.y; a[i][2]=u0.z; a[i][3]=u0.w;
                    a[i][4]=u1.x; a[i][5]=u1.y; a[i][6]=u1.z; a[i][7]=u1.w;
                } else {
                    #pragma unroll
                    for (int kk = 0; kk < 8; kk++) a[i][kk] = 0.f;
                }
                if (BN_IN) {
                    #pragma unroll
                    for (int kk = 0; kk < 8; kk++) {
                        float v = fmaf(a[i][kk], scale_s[kb + kk], shift_s[kb + kk]);
                        a[i][kk] = (v > 0.f) ? v : 0.01f * v;
                    }
                }
            }
            #pragma unroll
            for (int kk = 0; kk < 8; kk++) {
                float4 w0 = *reinterpret_cast<const float4*>(&w_s[(kb + kk) * 128 + c0]);
                float4 w1 = *reinterpret_cast<const float4*>(&w_s[(kb + kk) * 128 + c0 + 4]);
                float w[8] = {w0.x, w0.y, w0.z, w0.w, w1.x, w1.y, w1.z, w1.w};
                #pragma unroll
                for (int i = 0; i < 4; i++)
                    #pragma unroll
                    for (int j = 0; j < 8; j++) acc[i][j] = fmaf(a[i][kk], w[j], acc[i][j]);
            }
        }
        #pragma unroll
        for (int i = 0; i < 4; i++) {
            int r = r0 + i;
            if (r < N) {
                float v[8];
                #pragma unroll
                for (int j = 0; j < 8; j++) v[j] = acc[i][j] + bj[j];
                float4 o0 = {v[0], v[1], v[2], v[3]};
                float4 o1 = {v[4], v[5], v[6], v[7]};
                *reinterpret_cast<float4*>(&out[(size_t)r * 128 + c0]) = o0;
                *reinterpret_cast<float4*>(&out[(size_t)r * 128 + c0 + 4]) = o1;
                #pragma unroll
                for (int j = 0; j < 8; j++) { bsum[j] += v[j]; bsq[j] += v[j] * v[j]; }
            }
        }
    }
    __syncthreads();
    #pragma unroll
    for (int j = 0; j < 8; j++) red_s[ri * 128 + c0 + j] = bsum[j];
    __syncthreads();
    if (tid < 128) {
        float s = 0.f;
        #pragma unroll
        for (int i = 0; i < 16; i++) s += red_s[i * 128 + tid];
        partials[blockIdx.x * 256 + tid] = s;
    }
    __syncthreads();
    #pragma unroll
    for (int j = 0; j < 8; j++) red_s[ri * 128 + c0 + j] = bsq[j];
    __syncthreads();
    if (tid < 128) {
        float s = 0.f;
        #pragma unroll
        for (int i = 0; i < 16; i++) s += red_s[i * 128 + tid];
        partials[blockIdx.x * 256 + 128 + tid] = s;
    }
}

// ================================================================ BN stats reduce
__global__ __launch_bounds__(128) void reduce_stats_kernel(
    const float* __restrict__ partials, int NB, float invN,
    const float* __restrict__ g, const float* __restrict__ be,
    float* __restrict__ ss)
{
    int c = threadIdx.x;
    float s = 0.f, q = 0.f;
    for (int b = 0; b < NB; b++) {
        s += partials[b * 256 + c];
        q += partials[b * 256 + 128 + c];
    }
    float mean = s * invN;
    float var = fmaxf(q * invN - mean * mean, 0.f);
    float inv = rsqrtf(var + 1e-5f);
    float scale = g[c] * inv;
    ss[c] = scale;
    ss[128 + c] = be[c] - mean * scale;
}

// ================================================================ bn+lrelu elementwise
__global__ __launch_bounds__(256) void bn_lrelu_kernel(
    const float* __restrict__ U, const float* __restrict__ ss,
    float* __restrict__ xo, int total4)
{
    int i = blockIdx.x * 256 + threadIdx.x;
    if (i >= total4) return;
    int cq = (i & 31) * 4;
    float4 v = reinterpret_cast<const float4*>(U)[i];
    float s0 = ss[cq], s1 = ss[cq + 1], s2 = ss[cq + 2], s3 = ss[cq + 3];
    float h0 = ss[128 + cq], h1 = ss[129 + cq], h2 = ss[130 + cq], h3 = ss[131 + cq];
    v.x = fmaf(v.x, s0, h0); v.x = (v.x > 0.f) ? v.x : 0.01f * v.x;
    v.y = fmaf(v.y, s1, h1); v.y = (v.y > 0.f) ? v.y : 0.01f * v.y;
    v.z = fmaf(v.z, s2, h2); v.z = (v.z > 0.f) ? v.z : 0.01f * v.z;
    v.w = fmaf(v.w, s3, h3); v.w = (v.w > 0.f) ? v.w : 0.01f * v.w;
    reinterpret_cast<float4*>(xo)[i] = v;
}

// ================================================================ global add pool
// batch is sorted: run-length accumulate in registers, flush on graph change.
__global__ __launch_bounds__(256) void pool_kernel(
    const float* __restrict__ x3, const int* __restrict__ batch,
    float* __restrict__ pool, int N)
{
    int w = (blockIdx.x * 256 + threadIdx.x) >> 6;
    int lane = threadIdx.x & 63;
    int n0 = w * 32;
    if (n0 >= N) return;
    int n1 = min(n0 + 32, N);
    int c0 = lane * 2;
    float a0 = 0.f, a1 = 0.f;
    int cur = batch[n0];
    for (int n = n0; n < n1; ++n) {
        int b = batch[n];
        if (b != cur) {
            atomicAdd(&pool[(size_t)cur * 128 + c0], a0);
            atomicAdd(&pool[(size_t)cur * 128 + c0 + 1], a1);
            a0 = a1 = 0.f; cur = b;
        }
        float2 v = *reinterpret_cast<const float2*>(&x3[(size_t)n * 128 + c0]);
        a0 += v.x; a1 += v.y;
    }
    atomicAdd(&pool[(size_t)cur * 128 + c0], a0);
    atomicAdd(&pool[(size_t)cur * 128 + c0 + 1], a1);
}

// ================================================================ final
__global__ __launch_bounds__(256) void final_kernel(
    const float* __restrict__ x3, const float* __restrict__ pool,
    const int* __restrict__ batch, const float* __restrict__ wf,
    const float* __restrict__ bf, float* __restrict__ out, int N)
{
    __shared__ float wf_s[512];
    int tid = threadIdx.x;
    for (int i = tid; i < 512; i += 256) wf_s[i] = wf[i];
    __syncthreads();
    int wid = tid >> 6, lane = tid & 63;
    int n = blockIdx.x * 4 + wid;
    if (n >= N) return;
    int b = batch[n];
    float v0 = x3[(size_t)n * 128 + lane];
    float v1 = x3[(size_t)n * 128 + 64 + lane];
    float p0 = pool[(size_t)b * 128 + lane];
    float p1 = pool[(size_t)b * 128 + 64 + lane];
    float a0 = v0 * wf_s[lane * 2]       + v1 * wf_s[(64 + lane) * 2]
             + p0 * wf_s[(128 + lane) * 2] + p1 * wf_s[(192 + lane) * 2];
    float a1 = v0 * wf_s[lane * 2 + 1]       + v1 * wf_s[(64 + lane) * 2 + 1]
             + p0 * wf_s[(128 + lane) * 2 + 1] + p1 * wf_s[(192 + lane) * 2 + 1];
    #pragma unroll
    for (int off = 32; off >= 1; off >>= 1) {
        a0 += __shfl_down(a0, off);
        a1 += __shfl_down(a1, off);
    }
    if (lane == 0) {
        a0 += bf[0]; a1 += bf[1];
        float mx = fmaxf(a0, a1);
        float e0 = __expf(a0 - mx), e1 = __expf(a1 - mx);
        float inv = 1.f / (e0 + e1);
        out[(size_t)n * 2]     = e0 * inv;
        out[(size_t)n * 2 + 1] = e1 * inv;
    }
}

// ================================================================ launch
extern "C" void kernel_launch(void* const* d_in, const int* in_sizes, int n_in,
                              void* d_out, int out_size, void* d_ws, size_t ws_size,
                              hipStream_t stream)
{
    const float* x0    = (const float*)d_in[0];
    const int*   ei    = (const int*)d_in[1];
    const float* ea    = (const float*)d_in[2];
    const int*   batch = (const int*)d_in[3];
    const int E = in_sizes[1] / 2;
    const int N = in_sizes[3];
    const int* srcv = ei;
    const int* dstv = ei + E;
    const float* wf = (const float*)d_in[37];
    const float* bf = (const float*)d_in[38];
    float* ws = (float*)d_ws;

    // workspace layout
    float* buf[2] = { ws, ws + (size_t)N * 128 };
    float* poolb  = ws + (size_t)2 * N * 128;
    float* part   = poolb + (size_t)GNUM * 128;
    float* ss1    = part + (size_t)GEMM_BLOCKS * 256;
    float* ss2    = ss1 + 256;
    int*   off    = (int*)(ss2 + 256);          // N+1 ints
    int*   cursor = off + (N + 1);              // N ints
    int*   bsum   = cursor + N;                 // 128 ints
    int*   perm   = bsum + 128;                 // E ints
    float* out    = (float*)d_out;
    const float invN = 1.0f / (float)N;

    // ---- CSR build (by destination) ----
    hipMemsetAsync(off, 0, (size_t)(N + 1) * sizeof(int), stream);
    hist_kernel<<<(E + 255) / 256, 256, 0, stream>>>(dstv, off, E);
    const int n1 = N + 1;
    const int nb = (n1 + 1023) / 1024;
    scan_block_kernel<<<nb, 256, 0, stream>>>(off, bsum, n1);
    scan_carry_kernel<<<1, 128, 0, stream>>>(bsum, nb);
    scan_add_kernel<<<(n1 + 255) / 256, 256, 0, stream>>>(off, bsum, cursor, n1, N);
    scatter_kernel<<<(E + 255) / 256, 256, 0, stream>>>(dstv, cursor, perm, E);

    const int gather_blocks = (N + 3) / 4;   // 4 waves/block, 1 wave/node

    for (int l = 0; l < 3; l++) {
        const int C = (l == 0) ? 32 : 128;
        const float* xin = (l == 0) ? x0 : buf[(l + 1) & 1];
        float* agg  = buf[l & 1];
        float* T    = buf[(l + 1) & 1];   // k2 in-place: U aliases T
        float* xout = buf[l & 1];
        int bidx = 4 + l * 11;
        const float* epsp = (const float*)d_in[bidx + 0];
        const float* ew   = (const float*)d_in[bidx + 1];
        const float* eb   = (const float*)d_in[bidx + 2];
        const float* w1   = (const float*)d_in[bidx + 3];
        const float* b1   = (const float*)d_in[bidx + 4];
        const float* g1   = (const float*)d_in[bidx + 5];
        const float* be1  = (const float*)d_in[bidx + 6];
        const float* w2   = (const float*)d_in[bidx + 7];
        const float* b2   = (const float*)d_in[bidx + 8];
        const float* g2   = (const float*)d_in[bidx + 9];
        const float* be2  = (const float*)d_in[bidx + 10];

        if (C == 32)
            gather_kernel32<<<gather_blocks, 256, 0, stream>>>(
                ea, srcv, perm, off, ew, eb, epsp, xin, agg, N);
        else
            gather_kernel128<<<gather_blocks, 256, 0, stream>>>(
                ea, srcv, perm, off, ew, eb, epsp, xin, agg, N);

        if (C == 32)
            gemm_bn_kernel<32, false><<<GEMM_BLOCKS, 256, 0, stream>>>(agg, nullptr, w1, b1, T, part, N);
        else
            gemm_bn_kernel<128, false><<<GEMM_BLOCKS, 256, 0, stream>>>(agg, nullptr, w1, b1, T, part, N);
        reduce_stats_kernel<<<1, 128, 0, stream>>>(part, GEMM_BLOCKS, invN, g1, be1, ss1);
        gemm_bn_kernel<128, true><<<GEMM_BLOCKS, 256, 0, stream>>>(T, ss1, w2, b2, T, part, N);
        reduce_stats_kernel<<<1, 128, 0, stream>>>(part, GEMM_BLOCKS, invN, g2, be2, ss2);
        int t4 = N * 128 / 4;
        bn_lrelu_kernel<<<(t4 + 255) / 256, 256, 0, stream>>>(T, ss2, xout, t4);
    }
    hipMemsetAsync(poolb, 0, (size_t)GNUM * 128 * 4, stream);
    pool_kernel<<<((N + 31) / 32 * 64 + 255) / 256, 256, 0, stream>>>(buf[0], batch, poolb, N);
    final_kernel<<<(N + 3) / 4, 256, 0, stream>>>(buf[0], poolb, batch, wf, bf, out, N);
}

// Round 3
// 2405.990 us; speedup vs baseline: 3.7894x; 1.0403x over previous
//
#include <hip/hip_runtime.h>

#define GEMM_BLOCKS 512
#define GNUM 4096   // num graphs (fixed in reference)

// ================================================================ CSR build
__global__ __launch_bounds__(256) void hist_kernel(
    const int* __restrict__ dstv, int* __restrict__ cnt, int E)
{
    int i = blockIdx.x * 256 + threadIdx.x;
    if (i < E) atomicAdd(&cnt[dstv[i] + 1], 1);
}

__global__ __launch_bounds__(256) void scan_block_kernel(
    int* __restrict__ data, int* __restrict__ bsum, int n)
{
    __shared__ int s[256];
    int tid = threadIdx.x;
    int base = blockIdx.x * 1024 + tid * 4;
    int v[4]; int run = 0;
    #pragma unroll
    for (int i = 0; i < 4; i++) {
        int x = (base + i < n) ? data[base + i] : 0;
        run += x; v[i] = run;
    }
    s[tid] = run; __syncthreads();
    for (int off = 1; off < 256; off <<= 1) {
        int t = (tid >= off) ? s[tid - off] : 0;
        __syncthreads();
        s[tid] += t;
        __syncthreads();
    }
    int excl = s[tid] - run;
    #pragma unroll
    for (int i = 0; i < 4; i++)
        if (base + i < n) data[base + i] = v[i] + excl;
    if (tid == 255) bsum[blockIdx.x] = s[255];
}

__global__ __launch_bounds__(128) void scan_carry_kernel(int* __restrict__ bsum, int nb)
{
    __shared__ int s[128];
    int tid = threadIdx.x;
    int orig = (tid < nb) ? bsum[tid] : 0;
    s[tid] = orig; __syncthreads();
    for (int off = 1; off < 128; off <<= 1) {
        int t = (tid >= off) ? s[tid - off] : 0;
        __syncthreads();
        s[tid] += t;
        __syncthreads();
    }
    if (tid < nb) bsum[tid] = s[tid] - orig;
}

__global__ __launch_bounds__(256) void scan_add_kernel(
    int* __restrict__ data, const int* __restrict__ bsum,
    int* __restrict__ cursor, int n, int N)
{
    int i = blockIdx.x * 256 + threadIdx.x;
    if (i < n) {
        int v = data[i] + bsum[i >> 10];
        data[i] = v;
        if (i < N) cursor[i] = v;
    }
}

__global__ __launch_bounds__(256) void scatter_kernel(
    const int* __restrict__ dstv, int* __restrict__ cursor,
    int* __restrict__ perm, int E)
{
    int i = blockIdx.x * 256 + threadIdx.x;
    if (i < E) {
        int p = atomicAdd(&cursor[dstv[i]], 1);
        perm[p] = i;
    }
}

// ================================================================ reorder
// eap[p] = ea[perm[p]] (16 floats), srcp[p] = srcv[perm[p]].
// One float4 per thread; sequential writes, scattered 16B reads.
__global__ __launch_bounds__(256) void reorder_kernel(
    const float* __restrict__ ea, const int* __restrict__ srcv,
    const int* __restrict__ perm, float* __restrict__ eap,
    int* __restrict__ srcp, int E)
{
    int i = blockIdx.x * 256 + threadIdx.x;
    int p = i >> 2, q = i & 3;
    if (p >= E) return;
    int e = perm[p];
    float4 v = reinterpret_cast<const float4*>(ea)[e * 4 + q];
    reinterpret_cast<float4*>(eap)[p * 4 + q] = v;
    if (q == 0) srcp[p] = srcv[e];
}

// ================================================================ edge gather
// agg[n] = (1+eps)*x[n] + sum_{e: dst(e)=n} relu(x[src(e)] + ea[e]@ew + eb)
// One wave per node. RO: edge data pre-permuted into CSR order (sequential).

template<bool RO>
__global__ __launch_bounds__(256) void gather_kernel128(
    const float* __restrict__ ea, const int* __restrict__ srcv,
    const int* __restrict__ perm, const int* __restrict__ off,
    const float* __restrict__ ew, const float* __restrict__ ebias,
    const float* __restrict__ epsp, const float* __restrict__ x,
    float* __restrict__ agg, int N)
{
    int lane = threadIdx.x & 63;
    int n = __builtin_amdgcn_readfirstlane((int)((blockIdx.x * 256 + threadIdx.x) >> 6));
    if (n >= N) return;
    const int c0 = lane * 2;
    float ew0[16], ew1[16];
    #pragma unroll
    for (int k = 0; k < 16; k++) {
        float2 w = *reinterpret_cast<const float2*>(&ew[k * 128 + c0]);
        ew0[k] = w.x; ew1[k] = w.y;
    }
    const float eb0 = ebias[c0], eb1 = ebias[c0 + 1];
    float acc0 = 0.f, acc1 = 0.f;
    int p = off[n];
    const int end = off[n + 1];
    for (; p + 2 <= end; p += 2) {
        int e0 = RO ? p : perm[p];
        int e1 = RO ? (p + 1) : perm[p + 1];
        int s0 = srcv[e0], s1 = srcv[e1];
        const float4* ap0 = reinterpret_cast<const float4*>(ea + (size_t)e0 * 16);
        const float4* ap1 = reinterpret_cast<const float4*>(ea + (size_t)e1 * 16);
        float av[16], bv[16];
        #pragma unroll
        for (int q = 0; q < 4; q++) {
            float4 t = ap0[q]; av[4*q]=t.x; av[4*q+1]=t.y; av[4*q+2]=t.z; av[4*q+3]=t.w;
            float4 u = ap1[q]; bv[4*q]=u.x; bv[4*q+1]=u.y; bv[4*q+2]=u.z; bv[4*q+3]=u.w;
        }
        float2 xv0 = *reinterpret_cast<const float2*>(&x[(size_t)s0 * 128 + c0]);
        float2 xv1 = *reinterpret_cast<const float2*>(&x[(size_t)s1 * 128 + c0]);
        float u0 = eb0, u1 = eb1, w0 = eb0, w1 = eb1;
        #pragma unroll
        for (int k = 0; k < 16; k++) {
            u0 = fmaf(av[k], ew0[k], u0);
            u1 = fmaf(av[k], ew1[k], u1);
            w0 = fmaf(bv[k], ew0[k], w0);
            w1 = fmaf(bv[k], ew1[k], w1);
        }
        acc0 += fmaxf(xv0.x + u0, 0.f) + fmaxf(xv1.x + w0, 0.f);
        acc1 += fmaxf(xv0.y + u1, 0.f) + fmaxf(xv1.y + w1, 0.f);
    }
    if (p < end) {
        int e0 = RO ? p : perm[p];
        int s0 = srcv[e0];
        const float4* ap0 = reinterpret_cast<const float4*>(ea + (size_t)e0 * 16);
        float av[16];
        #pragma unroll
        for (int q = 0; q < 4; q++) {
            float4 t = ap0[q]; av[4*q]=t.x; av[4*q+1]=t.y; av[4*q+2]=t.z; av[4*q+3]=t.w;
        }
        float2 xv0 = *reinterpret_cast<const float2*>(&x[(size_t)s0 * 128 + c0]);
        float u0 = eb0, u1 = eb1;
        #pragma unroll
        for (int k = 0; k < 16; k++) {
            u0 = fmaf(av[k], ew0[k], u0);
            u1 = fmaf(av[k], ew1[k], u1);
        }
        acc0 += fmaxf(xv0.x + u0, 0.f);
        acc1 += fmaxf(xv0.y + u1, 0.f);
    }
    float2 xn = *reinterpret_cast<const float2*>(&x[(size_t)n * 128 + c0]);
    float s = 1.f + epsp[0];
    float2 o;
    o.x = fmaf(xn.x, s, acc0);
    o.y = fmaf(xn.y, s, acc1);
    *reinterpret_cast<float2*>(&agg[(size_t)n * 128 + c0]) = o;
}

// C = 32: half-wave per edge, 4 edges in flight (2 per half) for MLP.
template<bool RO>
__global__ __launch_bounds__(256) void gather_kernel32(
    const float* __restrict__ ea, const int* __restrict__ srcv,
    const int* __restrict__ perm, const int* __restrict__ off,
    const float* __restrict__ ew, const float* __restrict__ ebias,
    const float* __restrict__ epsp, const float* __restrict__ x,
    float* __restrict__ agg, int N)
{
    int lane = threadIdx.x & 63;
    int n = __builtin_amdgcn_readfirstlane((int)((blockIdx.x * 256 + threadIdx.x) >> 6));
    if (n >= N) return;
    const int h = lane >> 5;
    const int c = lane & 31;
    float ewr[16];
    #pragma unroll
    for (int k = 0; k < 16; k++) ewr[k] = ew[k * 32 + c];
    const float ebr = ebias[c];
    float acc = 0.f;
    const int p0 = off[n], end = off[n + 1];
    for (int p = p0; p < end; p += 4) {
        int pa = p + h, pb = p + 2 + h;
        bool va = pa < end, vb = pb < end;
        int ia = va ? pa : p;
        int ib = vb ? pb : p;
        int eA = RO ? ia : perm[ia];
        int eB = RO ? ib : perm[ib];
        int sa = srcv[eA], sb = srcv[eB];
        const float4* apA = reinterpret_cast<const float4*>(ea + (size_t)eA * 16);
        const float4* apB = reinterpret_cast<const float4*>(ea + (size_t)eB * 16);
        float av[16], bv[16];
        #pragma unroll
        for (int q = 0; q < 4; q++) {
            float4 t = apA[q]; av[4*q]=t.x; av[4*q+1]=t.y; av[4*q+2]=t.z; av[4*q+3]=t.w;
            float4 u = apB[q]; bv[4*q]=u.x; bv[4*q+1]=u.y; bv[4*q+2]=u.z; bv[4*q+3]=u.w;
        }
        float xa = x[(size_t)sa * 32 + c];
        float xb = x[(size_t)sb * 32 + c];
        float ua = ebr, ub = ebr;
        #pragma unroll
        for (int k = 0; k < 16; k++) {
            ua = fmaf(av[k], ewr[k], ua);
            ub = fmaf(bv[k], ewr[k], ub);
        }
        acc += va ? fmaxf(xa + ua, 0.f) : 0.f;
        acc += vb ? fmaxf(xb + ub, 0.f) : 0.f;
    }
    acc += __shfl_xor(acc, 32);
    if (lane < 32) {
        float s = 1.f + epsp[0];
        agg[(size_t)n * 32 + c] = fmaf(x[(size_t)n * 32 + c], s, acc);
    }
}

// ================================================================ GEMM + BN stats
template<int K, bool BN_IN>
__global__ __launch_bounds__(256) void gemm_bn_kernel(
    const float* __restrict__ A, const float* __restrict__ ss,
    const float* __restrict__ W, const float* __restrict__ bias,
    float* __restrict__ out, float* __restrict__ partials, int N)
{
    __shared__ float w_s[K * 128];
    __shared__ float red_s[16 * 128];
    __shared__ float scale_s[K];
    __shared__ float shift_s[K];
    const int tid = threadIdx.x;
    for (int i = tid; i < K * 128; i += 256) w_s[i] = W[i];
    if (BN_IN) {
        for (int i = tid; i < K; i += 256) { scale_s[i] = ss[i]; shift_s[i] = ss[K + i]; }
    }
    __syncthreads();
    const int ri = tid >> 4;
    const int ci = tid & 15;
    const int c0 = ci * 8;
    float bj[8];
    #pragma unroll
    for (int j = 0; j < 8; j++) bj[j] = bias[c0 + j];
    float bsum[8], bsq[8];
    #pragma unroll
    for (int j = 0; j < 8; j++) { bsum[j] = 0.f; bsq[j] = 0.f; }

    for (int row0 = blockIdx.x * 64; row0 < N; row0 += gridDim.x * 64) {
        const int r0 = row0 + ri * 4;
        float acc[4][8];
        #pragma unroll
        for (int i = 0; i < 4; i++)
            #pragma unroll
            for (int j = 0; j < 8; j++) acc[i][j] = 0.f;
        for (int kb = 0; kb < K; kb += 8) {
            float a[4][8];
            #pragma unroll
            for (int i = 0; i < 4; i++) {
                int r = r0 + i;
                if (r < N) {
                    float4 u0 = *reinterpret_cast<const float4*>(&A[(size_t)r * K + kb]);
                    float4 u1 = *reinterpret_cast<const float4*>(&A[(size_t)r * K + kb + 4]);
                    a[i][0]=u0.x; a[i][1]=u0.y; a[i][2]=u0.z; a[i][3]=u0.w;
                    a[i][4]=u1.x; a[i][5]=u1.y; a[i][6]=u1.z; a[i][7]=u1.w;
                } else {
                    #pragma unroll
                    for (int kk = 0; kk < 8; kk++) a[i][kk] = 0.f;
                }
                if (BN_IN) {
                    #pragma unroll
                    for (int kk = 0; kk < 8; kk++) {
                        float v = fmaf(a[i][kk], scale_s[kb + kk], shift_s[kb + kk]);
                        a[i][kk] = (v > 0.f) ? v : 0.01f * v;
                    }
                }
            }
            #pragma unroll
            for (int kk = 0; kk < 8; kk++) {
                float4 w0 = *reinterpret_cast<const float4*>(&w_s[(kb + kk) * 128 + c0]);
                float4 w1 = *reinterpret_cast<const float4*>(&w_s[(kb + kk) * 128 + c0 + 4]);
                float w[8] = {w0.x, w0.y, w0.z, w0.w, w1.x, w1.y, w1.z, w1.w};
                #pragma unroll
                for (int i = 0; i < 4; i++)
                    #pragma unroll
                    for (int j = 0; j < 8; j++) acc[i][j] = fmaf(a[i][kk], w[j], acc[i][j]);
            }
        }
        #pragma unroll
        for (int i = 0; i < 4; i++) {
            int r = r0 + i;
            if (r < N) {
                float v[8];
                #pragma unroll
                for (int j = 0; j < 8; j++) v[j] = acc[i][j] + bj[j];
                float4 o0 = {v[0], v[1], v[2], v[3]};
                float4 o1 = {v[4], v[5], v[6], v[7]};
                *reinterpret_cast<float4*>(&out[(size_t)r * 128 + c0]) = o0;
                *reinterpret_cast<float4*>(&out[(size_t)r * 128 + c0 + 4]) = o1;
                #pragma unroll
                for (int j = 0; j < 8; j++) { bsum[j] += v[j]; bsq[j] += v[j] * v[j]; }
            }
        }
    }
    __syncthreads();
    #pragma unroll
    for (int j = 0; j < 8; j++) red_s[ri * 128 + c0 + j] = bsum[j];
    __syncthreads();
    if (tid < 128) {
        float s = 0.f;
        #pragma unroll
        for (int i = 0; i < 16; i++) s += red_s[i * 128 + tid];
        partials[blockIdx.x * 256 + tid] = s;
    }
    __syncthreads();
    #pragma unroll
    for (int j = 0; j < 8; j++) red_s[ri * 128 + c0 + j] = bsq[j];
    __syncthreads();
    if (tid < 128) {
        float s = 0.f;
        #pragma unroll
        for (int i = 0; i < 16; i++) s += red_s[i * 128 + tid];
        partials[blockIdx.x * 256 + 128 + tid] = s;
    }
}

// ================================================================ BN stats reduce
__global__ __launch_bounds__(128) void reduce_stats_kernel(
    const float* __restrict__ partials, int NB, float invN,
    const float* __restrict__ g, const float* __restrict__ be,
    float* __restrict__ ss)
{
    int c = threadIdx.x;
    float s = 0.f, q = 0.f;
    for (int b = 0; b < NB; b++) {
        s += partials[b * 256 + c];
        q += partials[b * 256 + 128 + c];
    }
    float mean = s * invN;
    float var = fmaxf(q * invN - mean * mean, 0.f);
    float inv = rsqrtf(var + 1e-5f);
    float scale = g[c] * inv;
    ss[c] = scale;
    ss[128 + c] = be[c] - mean * scale;
}

// ================================================================ bn+lrelu elementwise
__global__ __launch_bounds__(256) void bn_lrelu_kernel(
    const float* __restrict__ U, const float* __restrict__ ss,
    float* __restrict__ xo, int total4)
{
    int i = blockIdx.x * 256 + threadIdx.x;
    if (i >= total4) return;
    int cq = (i & 31) * 4;
    float4 v = reinterpret_cast<const float4*>(U)[i];
    float s0 = ss[cq], s1 = ss[cq + 1], s2 = ss[cq + 2], s3 = ss[cq + 3];
    float h0 = ss[128 + cq], h1 = ss[129 + cq], h2 = ss[130 + cq], h3 = ss[131 + cq];
    v.x = fmaf(v.x, s0, h0); v.x = (v.x > 0.f) ? v.x : 0.01f * v.x;
    v.y = fmaf(v.y, s1, h1); v.y = (v.y > 0.f) ? v.y : 0.01f * v.y;
    v.z = fmaf(v.z, s2, h2); v.z = (v.z > 0.f) ? v.z : 0.01f * v.z;
    v.w = fmaf(v.w, s3, h3); v.w = (v.w > 0.f) ? v.w : 0.01f * v.w;
    reinterpret_cast<float4*>(xo)[i] = v;
}

// ================================================================ global add pool
__global__ __launch_bounds__(256) void pool_kernel(
    const float* __restrict__ x3, const int* __restrict__ batch,
    float* __restrict__ pool, int N)
{
    int w = (blockIdx.x * 256 + threadIdx.x) >> 6;
    int lane = threadIdx.x & 63;
    int n0 = w * 32;
    if (n0 >= N) return;
    int n1 = min(n0 + 32, N);
    int c0 = lane * 2;
    float a0 = 0.f, a1 = 0.f;
    int cur = batch[n0];
    for (int n = n0; n < n1; ++n) {
        int b = batch[n];
        if (b != cur) {
            atomicAdd(&pool[(size_t)cur * 128 + c0], a0);
            atomicAdd(&pool[(size_t)cur * 128 + c0 + 1], a1);
            a0 = a1 = 0.f; cur = b;
        }
        float2 v = *reinterpret_cast<const float2*>(&x3[(size_t)n * 128 + c0]);
        a0 += v.x; a1 += v.y;
    }
    atomicAdd(&pool[(size_t)cur * 128 + c0], a0);
    atomicAdd(&pool[(size_t)cur * 128 + c0 + 1], a1);
}

// ================================================================ final
__global__ __launch_bounds__(256) void final_kernel(
    const float* __restrict__ x3, const float* __restrict__ pool,
    const int* __restrict__ batch, const float* __restrict__ wf,
    const float* __restrict__ bf, float* __restrict__ out, int N)
{
    __shared__ float wf_s[512];
    int tid = threadIdx.x;
    for (int i = tid; i < 512; i += 256) wf_s[i] = wf[i];
    __syncthreads();
    int wid = tid >> 6, lane = tid & 63;
    int n = blockIdx.x * 4 + wid;
    if (n >= N) return;
    int b = batch[n];
    float v0 = x3[(size_t)n * 128 + lane];
    float v1 = x3[(size_t)n * 128 + 64 + lane];
    float p0 = pool[(size_t)b * 128 + lane];
    float p1 = pool[(size_t)b * 128 + 64 + lane];
    float a0 = v0 * wf_s[lane * 2]       + v1 * wf_s[(64 + lane) * 2]
             + p0 * wf_s[(128 + lane) * 2] + p1 * wf_s[(192 + lane) * 2];
    float a1 = v0 * wf_s[lane * 2 + 1]       + v1 * wf_s[(64 + lane) * 2 + 1]
             + p0 * wf_s[(128 + lane) * 2 + 1] + p1 * wf_s[(192 + lane) * 2 + 1];
    #pragma unroll
    for (int off = 32; off >= 1; off >>= 1) {
        a0 += __shfl_down(a0, off);
        a1 += __shfl_down(a1, off);
    }
    if (lane == 0) {
        a0 += bf[0]; a1 += bf[1];
        float mx = fmaxf(a0, a1);
        float e0 = __expf(a0 - mx), e1 = __expf(a1 - mx);
        float inv = 1.f / (e0 + e1);
        out[(size_t)n * 2]     = e0 * inv;
        out[(size_t)n * 2 + 1] = e1 * inv;
    }
}

// ================================================================ launch
extern "C" void kernel_launch(void* const* d_in, const int* in_sizes, int n_in,
                              void* d_out, int out_size, void* d_ws, size_t ws_size,
                              hipStream_t stream)
{
    const float* x0    = (const float*)d_in[0];
    const int*   ei    = (const int*)d_in[1];
    const float* ea    = (const float*)d_in[2];
    const int*   batch = (const int*)d_in[3];
    const int E = in_sizes[1] / 2;
    const int N = in_sizes[3];
    const int* srcv = ei;
    const int* dstv = ei + E;
    const float* wf = (const float*)d_in[37];
    const float* bf = (const float*)d_in[38];
    float* ws = (float*)d_ws;

    // full (reordered) layout needs:
    const size_t need_full = ((size_t)2 * N * 128 + (size_t)E * 16 + (size_t)GNUM * 128
                              + (size_t)GEMM_BLOCKS * 256 + 512
                              + (size_t)E + (size_t)(N + 1) + (size_t)N + 128 + (size_t)E)
                             * sizeof(float);
    const bool ro = (ws_size >= need_full);

    size_t o = 0;
    float* buf0  = ws + o; o += (size_t)N * 128;
    float* buf1  = ws + o; o += (size_t)N * 128;
    float* eap   = ws + o; o += ro ? (size_t)E * 16 : 0;   // 16B-aligned
    float* poolb = ws + o; o += (size_t)GNUM * 128;
    float* part  = ws + o; o += (size_t)GEMM_BLOCKS * 256;
    float* ss1   = ws + o; o += 256;
    float* ss2   = ws + o; o += 256;
    int*   srcp  = (int*)(ws + o); o += ro ? (size_t)E : 0;
    int*   off    = (int*)(ws + o); o += (size_t)(N + 1);
    int*   cursor = (int*)(ws + o); o += (size_t)N;
    int*   bsum   = (int*)(ws + o); o += 128;
    int*   perm   = (int*)(ws + o); o += (size_t)E;
    float* buf[2] = { buf0, buf1 };
    float* out    = (float*)d_out;
    const float invN = 1.0f / (float)N;

    // ---- CSR build (by destination) ----
    hipMemsetAsync(off, 0, (size_t)(N + 1) * sizeof(int), stream);
    hist_kernel<<<(E + 255) / 256, 256, 0, stream>>>(dstv, off, E);
    const int n1 = N + 1;
    const int nb = (n1 + 1023) / 1024;
    scan_block_kernel<<<nb, 256, 0, stream>>>(off, bsum, n1);
    scan_carry_kernel<<<1, 128, 0, stream>>>(bsum, nb);
    scan_add_kernel<<<(n1 + 255) / 256, 256, 0, stream>>>(off, bsum, cursor, n1, N);
    scatter_kernel<<<(E + 255) / 256, 256, 0, stream>>>(dstv, cursor, perm, E);
    if (ro)
        reorder_kernel<<<(E * 4 + 255) / 256, 256, 0, stream>>>(ea, srcv, perm, eap, srcp, E);

    const float* g_ea  = ro ? eap  : ea;
    const int*   g_src = ro ? srcp : srcv;

    const int gather_blocks = (N + 3) / 4;   // 4 waves/block, 1 wave/node

    for (int l = 0; l < 3; l++) {
        const int C = (l == 0) ? 32 : 128;
        const float* xin = (l == 0) ? x0 : buf[(l + 1) & 1];
        float* agg  = buf[l & 1];
        float* T    = buf[(l + 1) & 1];   // k2 in-place: U aliases T
        float* xout = buf[l & 1];
        int bidx = 4 + l * 11;
        const float* epsp = (const float*)d_in[bidx + 0];
        const float* ew   = (const float*)d_in[bidx + 1];
        const float* eb   = (const float*)d_in[bidx + 2];
        const float* w1   = (const float*)d_in[bidx + 3];
        const float* b1   = (const float*)d_in[bidx + 4];
        const float* g1   = (const float*)d_in[bidx + 5];
        const float* be1  = (const float*)d_in[bidx + 6];
        const float* w2   = (const float*)d_in[bidx + 7];
        const float* b2   = (const float*)d_in[bidx + 8];
        const float* g2   = (const float*)d_in[bidx + 9];
        const float* be2  = (const float*)d_in[bidx + 10];

        if (C == 32) {
            if (ro) gather_kernel32<true><<<gather_blocks, 256, 0, stream>>>(
                        g_ea, g_src, perm, off, ew, eb, epsp, xin, agg, N);
            else    gather_kernel32<false><<<gather_blocks, 256, 0, stream>>>(
                        g_ea, g_src, perm, off, ew, eb, epsp, xin, agg, N);
        } else {
            if (ro) gather_kernel128<true><<<gather_blocks, 256, 0, stream>>>(
                        g_ea, g_src, perm, off, ew, eb, epsp, xin, agg, N);
            else    gather_kernel128<false><<<gather_blocks, 256, 0, stream>>>(
                        g_ea, g_src, perm, off, ew, eb, epsp, xin, agg, N);
        }

        if (C == 32)
            gemm_bn_kernel<32, false><<<GEMM_BLOCKS, 256, 0, stream>>>(agg, nullptr, w1, b1, T, part, N);
        else
            gemm_bn_kernel<128, false><<<GEMM_BLOCKS, 256, 0, stream>>>(agg, nullptr, w1, b1, T, part, N);
        reduce_stats_kernel<<<1, 128, 0, stream>>>(part, GEMM_BLOCKS, invN, g1, be1, ss1);
        gemm_bn_kernel<128, true><<<GEMM_BLOCKS, 256, 0, stream>>>(T, ss1, w2, b2, T, part, N);
        reduce_stats_kernel<<<1, 128, 0, stream>>>(part, GEMM_BLOCKS, invN, g2, be2, ss2);
        int t4 = N * 128 / 4;
        bn_lrelu_kernel<<<(t4 + 255) / 256, 256, 0, stream>>>(T, ss2, xout, t4);
    }
    hipMemsetAsync(poolb, 0, (size_t)GNUM * 128 * 4, stream);
    pool_kernel<<<((N + 31) / 32 * 64 + 255) / 256, 256, 0, stream>>>(buf[0], batch, poolb, N);
    final_kernel<<<(N + 3) / 4, 256, 0, stream>>>(buf[0], poolb, batch, wf, bf, out, N);
}

// Round 5
// 1513.787 us; speedup vs baseline: 6.0228x; 1.5894x over previous
//
#include <hip/hip_runtime.h>

#define GEMM_GRID 512
#define GNUM 4096   // num graphs (fixed in reference)

typedef __attribute__((ext_vector_type(8))) short short8_t;
typedef __attribute__((ext_vector_type(4))) float f32x4;

__device__ __forceinline__ float bf2f(unsigned short u) {
    union { unsigned int i; float f; } v; v.i = ((unsigned int)u) << 16; return v.f;
}
__device__ __forceinline__ unsigned short f2bf(float f) {
    union { float f; unsigned int i; } v; v.f = f;
    unsigned int b = v.i + 0x7FFFu + ((v.i >> 16) & 1u);
    return (unsigned short)(b >> 16);
}

// ================================================================ CSR build
__global__ __launch_bounds__(256) void hist_kernel(
    const int* __restrict__ dstv, int* __restrict__ cnt, int E)
{
    int i = blockIdx.x * 256 + threadIdx.x;
    if (i < E) atomicAdd(&cnt[dstv[i] + 1], 1);
}

__global__ __launch_bounds__(256) void scan_block_kernel(
    int* __restrict__ data, int* __restrict__ bsum, int n)
{
    __shared__ int s[256];
    int tid = threadIdx.x;
    int base = blockIdx.x * 1024 + tid * 4;
    int v[4]; int run = 0;
    #pragma unroll
    for (int i = 0; i < 4; i++) {
        int x = (base + i < n) ? data[base + i] : 0;
        run += x; v[i] = run;
    }
    s[tid] = run; __syncthreads();
    for (int off = 1; off < 256; off <<= 1) {
        int t = (tid >= off) ? s[tid - off] : 0;
        __syncthreads();
        s[tid] += t;
        __syncthreads();
    }
    int excl = s[tid] - run;
    #pragma unroll
    for (int i = 0; i < 4; i++)
        if (base + i < n) data[base + i] = v[i] + excl;
    if (tid == 255) bsum[blockIdx.x] = s[255];
}

__global__ __launch_bounds__(128) void scan_carry_kernel(int* __restrict__ bsum, int nb)
{
    __shared__ int s[128];
    int tid = threadIdx.x;
    int orig = (tid < nb) ? bsum[tid] : 0;
    s[tid] = orig; __syncthreads();
    for (int off = 1; off < 128; off <<= 1) {
        int t = (tid >= off) ? s[tid - off] : 0;
        __syncthreads();
        s[tid] += t;
        __syncthreads();
    }
    if (tid < nb) bsum[tid] = s[tid] - orig;
}

__global__ __launch_bounds__(256) void scan_add_kernel(
    int* __restrict__ data, const int* __restrict__ bsum,
    int* __restrict__ cursor, int n, int N)
{
    int i = blockIdx.x * 256 + threadIdx.x;
    if (i < n) {
        int v = data[i] + bsum[i >> 10];
        data[i] = v;
        if (i < N) cursor[i] = v;
    }
}

__global__ __launch_bounds__(256) void scatter_kernel(
    const int* __restrict__ dstv, int* __restrict__ cursor,
    int* __restrict__ perm, int E)
{
    int i = blockIdx.x * 256 + threadIdx.x;
    if (i < E) {
        int p = atomicAdd(&cursor[dstv[i]], 1);
        perm[p] = i;
    }
}

// ================================================================ reorder
__global__ __launch_bounds__(256) void reorder_kernel(
    const float* __restrict__ ea, const int* __restrict__ srcv,
    const int* __restrict__ perm, float* __restrict__ eap,
    int* __restrict__ srcp, int E)
{
    int i = blockIdx.x * 256 + threadIdx.x;
    int p = i >> 2, q = i & 3;
    if (p >= E) return;
    int e = perm[p];
    float4 v = reinterpret_cast<const float4*>(ea)[e * 4 + q];
    reinterpret_cast<float4*>(eap)[p * 4 + q] = v;
    if (q == 0) srcp[p] = srcv[e];
}

// ================================================================ edge gather (fp32)
template<bool RO>
__global__ __launch_bounds__(256) void gather_kernel128(
    const float* __restrict__ ea, const int* __restrict__ srcv,
    const int* __restrict__ perm, const int* __restrict__ off,
    const float* __restrict__ ew, const float* __restrict__ ebias,
    const float* __restrict__ epsp, const float* __restrict__ x,
    float* __restrict__ agg, int N)
{
    int lane = threadIdx.x & 63;
    int n = __builtin_amdgcn_readfirstlane((int)((blockIdx.x * 256 + threadIdx.x) >> 6));
    if (n >= N) return;
    const int c0 = lane * 2;
    float ew0[16], ew1[16];
    #pragma unroll
    for (int k = 0; k < 16; k++) {
        float2 w = *reinterpret_cast<const float2*>(&ew[k * 128 + c0]);
        ew0[k] = w.x; ew1[k] = w.y;
    }
    const float eb0 = ebias[c0], eb1 = ebias[c0 + 1];
    float acc0 = 0.f, acc1 = 0.f;
    int p = off[n];
    const int end = off[n + 1];
    for (; p + 2 <= end; p += 2) {
        int e0 = RO ? p : perm[p];
        int e1 = RO ? (p + 1) : perm[p + 1];
        int s0 = srcv[e0], s1 = srcv[e1];
        const float4* ap0 = reinterpret_cast<const float4*>(ea + (size_t)e0 * 16);
        const float4* ap1 = reinterpret_cast<const float4*>(ea + (size_t)e1 * 16);
        float av[16], bv[16];
        #pragma unroll
        for (int q = 0; q < 4; q++) {
            float4 t = ap0[q]; av[4*q]=t.x; av[4*q+1]=t.y; av[4*q+2]=t.z; av[4*q+3]=t.w;
            float4 u = ap1[q]; bv[4*q]=u.x; bv[4*q+1]=u.y; bv[4*q+2]=u.z; bv[4*q+3]=u.w;
        }
        float2 xv0 = *reinterpret_cast<const float2*>(&x[(size_t)s0 * 128 + c0]);
        float2 xv1 = *reinterpret_cast<const float2*>(&x[(size_t)s1 * 128 + c0]);
        float u0 = eb0, u1 = eb1, w0 = eb0, w1 = eb1;
        #pragma unroll
        for (int k = 0; k < 16; k++) {
            u0 = fmaf(av[k], ew0[k], u0);
            u1 = fmaf(av[k], ew1[k], u1);
            w0 = fmaf(bv[k], ew0[k], w0);
            w1 = fmaf(bv[k], ew1[k], w1);
        }
        acc0 += fmaxf(xv0.x + u0, 0.f) + fmaxf(xv1.x + w0, 0.f);
        acc1 += fmaxf(xv0.y + u1, 0.f) + fmaxf(xv1.y + w1, 0.f);
    }
    if (p < end) {
        int e0 = RO ? p : perm[p];
        int s0 = srcv[e0];
        const float4* ap0 = reinterpret_cast<const float4*>(ea + (size_t)e0 * 16);
        float av[16];
        #pragma unroll
        for (int q = 0; q < 4; q++) {
            float4 t = ap0[q]; av[4*q]=t.x; av[4*q+1]=t.y; av[4*q+2]=t.z; av[4*q+3]=t.w;
        }
        float2 xv0 = *reinterpret_cast<const float2*>(&x[(size_t)s0 * 128 + c0]);
        float u0 = eb0, u1 = eb1;
        #pragma unroll
        for (int k = 0; k < 16; k++) {
            u0 = fmaf(av[k], ew0[k], u0);
            u1 = fmaf(av[k], ew1[k], u1);
        }
        acc0 += fmaxf(xv0.x + u0, 0.f);
        acc1 += fmaxf(xv0.y + u1, 0.f);
    }
    float2 xn = *reinterpret_cast<const float2*>(&x[(size_t)n * 128 + c0]);
    float s = 1.f + epsp[0];
    float2 o;
    o.x = fmaf(xn.x, s, acc0);
    o.y = fmaf(xn.y, s, acc1);
    *reinterpret_cast<float2*>(&agg[(size_t)n * 128 + c0]) = o;
}

// C = 32: half-wave per edge, 4 independent chains per half (8 edges/iter).
template<bool RO>
__global__ __launch_bounds__(256) void gather_kernel32(
    const float* __restrict__ ea, const int* __restrict__ srcv,
    const int* __restrict__ perm, const int* __restrict__ off,
    const float* __restrict__ ew, const float* __restrict__ ebias,
    const float* __restrict__ epsp, const float* __restrict__ x,
    float* __restrict__ agg, int N)
{
    int lane = threadIdx.x & 63;
    int n = __builtin_amdgcn_readfirstlane((int)((blockIdx.x * 256 + threadIdx.x) >> 6));
    if (n >= N) return;
    const int h = lane >> 5;
    const int c = lane & 31;
    float ewr[16];
    #pragma unroll
    for (int k = 0; k < 16; k++) ewr[k] = ew[k * 32 + c];
    const float ebr = ebias[c];
    float acc = 0.f;
    const int p0 = off[n], end = off[n + 1];
    for (int p = p0; p < end; p += 8) {
        int i0 = p + h, i1 = p + 2 + h, i2 = p + 4 + h, i3 = p + 6 + h;
        bool v0 = i0 < end, v1 = i1 < end, v2 = i2 < end, v3 = i3 < end;
        int j0 = v0 ? i0 : p, j1 = v1 ? i1 : p, j2 = v2 ? i2 : p, j3 = v3 ? i3 : p;
        int e0 = RO ? j0 : perm[j0];
        int e1 = RO ? j1 : perm[j1];
        int e2 = RO ? j2 : perm[j2];
        int e3 = RO ? j3 : perm[j3];
        int s0 = srcv[e0], s1 = srcv[e1], s2 = srcv[e2], s3 = srcv[e3];
        const float4* a0p = reinterpret_cast<const float4*>(ea + (size_t)e0 * 16);
        const float4* a1p = reinterpret_cast<const float4*>(ea + (size_t)e1 * 16);
        const float4* a2p = reinterpret_cast<const float4*>(ea + (size_t)e2 * 16);
        const float4* a3p = reinterpret_cast<const float4*>(ea + (size_t)e3 * 16);
        float a0v[16], a1v[16], a2v[16], a3v[16];
        #pragma unroll
        for (int q = 0; q < 4; q++) {
            float4 t0 = a0p[q]; a0v[4*q]=t0.x; a0v[4*q+1]=t0.y; a0v[4*q+2]=t0.z; a0v[4*q+3]=t0.w;
            float4 t1 = a1p[q]; a1v[4*q]=t1.x; a1v[4*q+1]=t1.y; a1v[4*q+2]=t1.z; a1v[4*q+3]=t1.w;
            float4 t2 = a2p[q]; a2v[4*q]=t2.x; a2v[4*q+1]=t2.y; a2v[4*q+2]=t2.z; a2v[4*q+3]=t2.w;
            float4 t3 = a3p[q]; a3v[4*q]=t3.x; a3v[4*q+1]=t3.y; a3v[4*q+2]=t3.z; a3v[4*q+3]=t3.w;
        }
        float x0v = x[(size_t)s0 * 32 + c];
        float x1v = x[(size_t)s1 * 32 + c];
        float x2v = x[(size_t)s2 * 32 + c];
        float x3v = x[(size_t)s3 * 32 + c];
        float u0 = ebr, u1 = ebr, u2 = ebr, u3 = ebr;
        #pragma unroll
        for (int k = 0; k < 16; k++) {
            u0 = fmaf(a0v[k], ewr[k], u0);
            u1 = fmaf(a1v[k], ewr[k], u1);
            u2 = fmaf(a2v[k], ewr[k], u2);
            u3 = fmaf(a3v[k], ewr[k], u3);
        }
        acc += v0 ? fmaxf(x0v + u0, 0.f) : 0.f;
        acc += v1 ? fmaxf(x1v + u1, 0.f) : 0.f;
        acc += v2 ? fmaxf(x2v + u2, 0.f) : 0.f;
        acc += v3 ? fmaxf(x3v + u3, 0.f) : 0.f;
    }
    acc += __shfl_xor(acc, 32);
    if (lane < 32) {
        float s = 1.f + epsp[0];
        agg[(size_t)n * 32 + c] = fmaf(x[(size_t)n * 32 + c], s, acc);
    }
}

// ================================================================ MFMA GEMM (split-A) + BN stats
// out[N,128](fp32) = f(A)[N,K](fp32) @ W[K,128] + bias, W rounded to bf16,
// A split into bf16 hi+lo (two MFMAs -> ~fp32-accurate A).
// f = identity or lrelu(bn(.)) via ss[2K] at staging. In-place safe (out==A).
// Column sum/sumsq of out accumulated into stats[256] via end-of-kernel atomics.
// Tile: 32 rows x 128 cols; wave w: rows (w&1)*16.., cols (w>>1)*64..
template<int K, bool BN_IN>
__global__ __launch_bounds__(256, 3) void gemm_mfma_kernel(
    const float* __restrict__ A, const float* __restrict__ ss,
    const float* __restrict__ W, const float* __restrict__ bias,
    float* __restrict__ out, float* __restrict__ stats, int N, int ntiles)
{
    constexpr int PA = K + 8;                  // LDS pitch in bf16 elems
    __shared__ unsigned short As_hi[32 * PA];
    __shared__ unsigned short As_lo[32 * PA];
    __shared__ unsigned short Wt[128 * PA];    // Wt[n][k]
    __shared__ float scale_s[K];
    __shared__ float shift_s[K];
    const int tid = threadIdx.x;
    const int w = tid >> 6;
    const int lane = tid & 63;
    const int quad = lane >> 4;
    const int l16 = lane & 15;
    const int rbase = (w & 1) * 16;
    const int nbase = (w >> 1) * 4;

    for (int idx = tid; idx < K * 128; idx += 256) {
        int k = idx >> 7, nn = idx & 127;
        Wt[nn * PA + k] = f2bf(W[idx]);
    }
    if (BN_IN) {
        for (int i = tid; i < K; i += 256) { scale_s[i] = ss[i]; shift_s[i] = ss[K + i]; }
    }
    float bcol[4];
    #pragma unroll
    for (int nt = 0; nt < 4; nt++) bcol[nt] = bias[(nbase + nt) * 16 + l16];
    float csum[4] = {0.f, 0.f, 0.f, 0.f}, csq[4] = {0.f, 0.f, 0.f, 0.f};

    constexpr int C8 = K / 8;

    for (int tile = blockIdx.x; tile < ntiles; tile += gridDim.x) {
        const int row0 = tile * 32;
        __syncthreads();
        for (int cid = tid; cid < 32 * C8; cid += 256) {
            int row = cid / C8, c8 = cid % C8;
            int r = row0 + row;
            float f[8];
            if (r < N) {
                float4 u0 = *reinterpret_cast<const float4*>(&A[(size_t)r * K + c8 * 8]);
                float4 u1 = *reinterpret_cast<const float4*>(&A[(size_t)r * K + c8 * 8 + 4]);
                f[0]=u0.x; f[1]=u0.y; f[2]=u0.z; f[3]=u0.w;
                f[4]=u1.x; f[5]=u1.y; f[6]=u1.z; f[7]=u1.w;
            } else {
                #pragma unroll
                for (int j = 0; j < 8; j++) f[j] = 0.f;
            }
            if (BN_IN) {
                int kb = c8 * 8;
                #pragma unroll
                for (int j = 0; j < 8; j++) {
                    float v = fmaf(f[j], scale_s[kb + j], shift_s[kb + j]);
                    f[j] = (v > 0.f) ? v : 0.01f * v;
                }
            }
            unsigned int hi[4], lo[4];
            #pragma unroll
            for (int j = 0; j < 4; j++) {
                unsigned short h0 = f2bf(f[2*j]);
                unsigned short h1 = f2bf(f[2*j + 1]);
                unsigned short l0 = f2bf(f[2*j]     - bf2f(h0));
                unsigned short l1 = f2bf(f[2*j + 1] - bf2f(h1));
                hi[j] = (unsigned int)h0 | ((unsigned int)h1 << 16);
                lo[j] = (unsigned int)l0 | ((unsigned int)l1 << 16);
            }
            *reinterpret_cast<uint4*>(&As_hi[row * PA + c8 * 8]) = make_uint4(hi[0], hi[1], hi[2], hi[3]);
            *reinterpret_cast<uint4*>(&As_lo[row * PA + c8 * 8]) = make_uint4(lo[0], lo[1], lo[2], lo[3]);
        }
        __syncthreads();

        f32x4 acc[4];
        #pragma unroll
        for (int nt = 0; nt < 4; nt++) { f32x4 z = {0.f,0.f,0.f,0.f}; acc[nt] = z; }
        #pragma unroll
        for (int chunk = 0; chunk < K / 32; chunk++) {
            short8_t ahi = *reinterpret_cast<const short8_t*>(
                &As_hi[(rbase + l16) * PA + chunk * 32 + quad * 8]);
            short8_t alo = *reinterpret_cast<const short8_t*>(
                &As_lo[(rbase + l16) * PA + chunk * 32 + quad * 8]);
            #pragma unroll
            for (int nt = 0; nt < 4; nt++) {
                short8_t bfr = *reinterpret_cast<const short8_t*>(
                    &Wt[((nbase + nt) * 16 + l16) * PA + chunk * 32 + quad * 8]);
                acc[nt] = __builtin_amdgcn_mfma_f32_16x16x32_bf16(alo, bfr, acc[nt], 0, 0, 0);
                acc[nt] = __builtin_amdgcn_mfma_f32_16x16x32_bf16(ahi, bfr, acc[nt], 0, 0, 0);
            }
        }
        const int rb = row0 + rbase + quad * 4;
        #pragma unroll
        for (int nt = 0; nt < 4; nt++) {
            #pragma unroll
            for (int rg = 0; rg < 4; rg++) {
                int r = rb + rg;
                if (r < N) {
                    float v = acc[nt][rg] + bcol[nt];
                    out[(size_t)r * 128 + (nbase + nt) * 16 + l16] = v;
                    csum[nt] += v; csq[nt] += v * v;
                }
            }
        }
    }
    // stats: reduce rows across quads (same col) then one atomic per col
    #pragma unroll
    for (int nt = 0; nt < 4; nt++) {
        float s = csum[nt]; s += __shfl_xor(s, 16); s += __shfl_xor(s, 32);
        float q = csq[nt];  q += __shfl_xor(q, 16); q += __shfl_xor(q, 32);
        if (quad == 0) {
            int col = (nbase + nt) * 16 + l16;
            atomicAdd(&stats[col], s);
            atomicAdd(&stats[128 + col], q);
        }
    }
}

// ================================================================ BN transform
__global__ __launch_bounds__(128) void transform_stats(
    const float* __restrict__ stats, float invN,
    const float* __restrict__ g, const float* __restrict__ be,
    float* __restrict__ ssout)
{
    int c = threadIdx.x;
    float mean = stats[c] * invN;
    float var = fmaxf(stats[128 + c] * invN - mean * mean, 0.f);
    float inv = rsqrtf(var + 1e-5f);
    float sc = g[c] * inv;
    ssout[c] = sc;
    ssout[128 + c] = be[c] - mean * sc;
}

// ================================================================ bn+lrelu elementwise (fp32)
__global__ __launch_bounds__(256) void bn_lrelu_kernel(
    const float* __restrict__ U, const float* __restrict__ ss,
    float* __restrict__ xo, int total4)
{
    int i = blockIdx.x * 256 + threadIdx.x;
    if (i >= total4) return;
    int cq = (i & 31) * 4;
    float4 v = reinterpret_cast<const float4*>(U)[i];
    float s0 = ss[cq], s1 = ss[cq + 1], s2 = ss[cq + 2], s3 = ss[cq + 3];
    float h0 = ss[128 + cq], h1 = ss[129 + cq], h2 = ss[130 + cq], h3 = ss[131 + cq];
    v.x = fmaf(v.x, s0, h0); v.x = (v.x > 0.f) ? v.x : 0.01f * v.x;
    v.y = fmaf(v.y, s1, h1); v.y = (v.y > 0.f) ? v.y : 0.01f * v.y;
    v.z = fmaf(v.z, s2, h2); v.z = (v.z > 0.f) ? v.z : 0.01f * v.z;
    v.w = fmaf(v.w, s3, h3); v.w = (v.w > 0.f) ? v.w : 0.01f * v.w;
    reinterpret_cast<float4*>(xo)[i] = v;
}

// ================================================================ global add pool
__global__ __launch_bounds__(256) void pool_kernel(
    const float* __restrict__ x3, const int* __restrict__ batch,
    float* __restrict__ pool, int N)
{
    int w = (blockIdx.x * 256 + threadIdx.x) >> 6;
    int lane = threadIdx.x & 63;
    int n0 = w * 32;
    if (n0 >= N) return;
    int n1 = min(n0 + 32, N);
    int c0 = lane * 2;
    float a0 = 0.f, a1 = 0.f;
    int cur = batch[n0];
    for (int n = n0; n < n1; ++n) {
        int b = batch[n];
        if (b != cur) {
            atomicAdd(&pool[(size_t)cur * 128 + c0], a0);
            atomicAdd(&pool[(size_t)cur * 128 + c0 + 1], a1);
            a0 = a1 = 0.f; cur = b;
        }
        float2 v = *reinterpret_cast<const float2*>(&x3[(size_t)n * 128 + c0]);
        a0 += v.x; a1 += v.y;
    }
    atomicAdd(&pool[(size_t)cur * 128 + c0], a0);
    atomicAdd(&pool[(size_t)cur * 128 + c0 + 1], a1);
}

// ================================================================ final
__global__ __launch_bounds__(256) void final_kernel(
    const float* __restrict__ x3, const float* __restrict__ pool,
    const int* __restrict__ batch, const float* __restrict__ wf,
    const float* __restrict__ bf, float* __restrict__ out, int N)
{
    __shared__ float wf_s[512];
    int tid = threadIdx.x;
    for (int i = tid; i < 512; i += 256) wf_s[i] = wf[i];
    __syncthreads();
    int wid = tid >> 6, lane = tid & 63;
    int n = blockIdx.x * 4 + wid;
    if (n >= N) return;
    int b = batch[n];
    float v0 = x3[(size_t)n * 128 + lane];
    float v1 = x3[(size_t)n * 128 + 64 + lane];
    float p0 = pool[(size_t)b * 128 + lane];
    float p1 = pool[(size_t)b * 128 + 64 + lane];
    float a0 = v0 * wf_s[lane * 2]       + v1 * wf_s[(64 + lane) * 2]
             + p0 * wf_s[(128 + lane) * 2] + p1 * wf_s[(192 + lane) * 2];
    float a1 = v0 * wf_s[lane * 2 + 1]       + v1 * wf_s[(64 + lane) * 2 + 1]
             + p0 * wf_s[(128 + lane) * 2 + 1] + p1 * wf_s[(192 + lane) * 2 + 1];
    #pragma unroll
    for (int off = 32; off >= 1; off >>= 1) {
        a0 += __shfl_down(a0, off);
        a1 += __shfl_down(a1, off);
    }
    if (lane == 0) {
        a0 += bf[0]; a1 += bf[1];
        float mx = fmaxf(a0, a1);
        float e0 = __expf(a0 - mx), e1 = __expf(a1 - mx);
        float inv = 1.f / (e0 + e1);
        out[(size_t)n * 2]     = e0 * inv;
        out[(size_t)n * 2 + 1] = e1 * inv;
    }
}

// ================================================================ launch
extern "C" void kernel_launch(void* const* d_in, const int* in_sizes, int n_in,
                              void* d_out, int out_size, void* d_ws, size_t ws_size,
                              hipStream_t stream)
{
    const float* x0    = (const float*)d_in[0];
    const int*   ei    = (const int*)d_in[1];
    const float* ea    = (const float*)d_in[2];
    const int*   batch = (const int*)d_in[3];
    const int E = in_sizes[1] / 2;
    const int N = in_sizes[3];
    const int* srcv = ei;
    const int* dstv = ei + E;
    const float* wf = (const float*)d_in[37];
    const float* bfp = (const float*)d_in[38];
    float* out = (float*)d_out;
    const float invN = 1.0f / (float)N;
    const int ntiles = (N + 31) / 32;

    // ---- workspace layout (floats) ----
    const size_t base_f = (size_t)2 * N * 128 + (size_t)GNUM * 128 + 12 * 256
                        + (size_t)(N + 1) + (size_t)N + 128 + (size_t)E;
    const size_t full_f = base_f + (size_t)E * 16 + (size_t)E;
    const bool ro = (ws_size >= full_f * 4);

    float* ws = (float*)d_ws;
    size_t o = 0;
    float* xA    = ws + o; o += (size_t)N * 128;
    float* xB    = ws + o; o += (size_t)N * 128;
    float* eap   = ws + o; o += ro ? (size_t)E * 16 : 0;
    float* poolb = ws + o; o += (size_t)GNUM * 128;
    float* statsb= ws + o; o += 6 * 256;
    float* ssb   = ws + o; o += 6 * 256;
    int* srcp    = (int*)(ws + o); o += ro ? (size_t)E : 0;
    int* off     = (int*)(ws + o); o += (size_t)(N + 1);
    int* cursor  = (int*)(ws + o); o += (size_t)N;
    int* bsumb   = (int*)(ws + o); o += 128;
    int* perm    = (int*)(ws + o);

    // ---- CSR build (by destination) ----
    hipMemsetAsync(off, 0, (size_t)(N + 1) * sizeof(int), stream);
    hipMemsetAsync(statsb, 0, (size_t)6 * 256 * sizeof(float), stream);
    hipMemsetAsync(poolb, 0, (size_t)GNUM * 128 * sizeof(float), stream);
    hist_kernel<<<(E + 255) / 256, 256, 0, stream>>>(dstv, off, E);
    const int n1 = N + 1;
    const int nb = (n1 + 1023) / 1024;
    scan_block_kernel<<<nb, 256, 0, stream>>>(off, bsumb, n1);
    scan_carry_kernel<<<1, 128, 0, stream>>>(bsumb, nb);
    scan_add_kernel<<<(n1 + 255) / 256, 256, 0, stream>>>(off, bsumb, cursor, n1, N);
    scatter_kernel<<<(E + 255) / 256, 256, 0, stream>>>(dstv, cursor, perm, E);
    if (ro)
        reorder_kernel<<<(E * 4 + 255) / 256, 256, 0, stream>>>(ea, srcv, perm, eap, srcp, E);

    const float* g_ea  = ro ? eap  : ea;
    const int*   g_src = ro ? srcp : srcv;
    const int gather_blocks = (N + 3) / 4;

    for (int l = 0; l < 3; l++) {
        const int C = (l == 0) ? 32 : 128;
        int bidx = 4 + l * 11;
        const float* epsp = (const float*)d_in[bidx + 0];
        const float* ew   = (const float*)d_in[bidx + 1];
        const float* eb   = (const float*)d_in[bidx + 2];
        const float* w1   = (const float*)d_in[bidx + 3];
        const float* b1   = (const float*)d_in[bidx + 4];
        const float* g1   = (const float*)d_in[bidx + 5];
        const float* be1  = (const float*)d_in[bidx + 6];
        const float* w2   = (const float*)d_in[bidx + 7];
        const float* b2   = (const float*)d_in[bidx + 8];
        const float* g2   = (const float*)d_in[bidx + 9];
        const float* be2  = (const float*)d_in[bidx + 10];
        float* st1 = statsb + (size_t)(l * 2) * 256;
        float* st2 = statsb + (size_t)(l * 2 + 1) * 256;
        float* ss1 = ssb + (size_t)(l * 2) * 256;
        float* ss2 = ssb + (size_t)(l * 2 + 1) * 256;

        // gather: x -> agg
        if (C == 32) {
            // x = x0 (input), agg -> xB [N,32]
            if (ro) gather_kernel32<true><<<gather_blocks, 256, 0, stream>>>(
                        g_ea, g_src, perm, off, ew, eb, epsp, x0, xB, N);
            else    gather_kernel32<false><<<gather_blocks, 256, 0, stream>>>(
                        g_ea, g_src, perm, off, ew, eb, epsp, x0, xB, N);
            // gemm1: xB[N,32] @ w1 -> xA[N,128]
            gemm_mfma_kernel<32, false><<<GEMM_GRID, 256, 0, stream>>>(
                xB, nullptr, w1, b1, xA, st1, N, ntiles);
        } else {
            // x = xB (prev layer out), agg -> xA
            if (ro) gather_kernel128<true><<<gather_blocks, 256, 0, stream>>>(
                        g_ea, g_src, perm, off, ew, eb, epsp, xB, xA, N);
            else    gather_kernel128<false><<<gather_blocks, 256, 0, stream>>>(
                        g_ea, g_src, perm, off, ew, eb, epsp, xB, xA, N);
            // gemm1: xA @ w1 -> xA (in-place)
            gemm_mfma_kernel<128, false><<<GEMM_GRID, 256, 0, stream>>>(
                xA, nullptr, w1, b1, xA, st1, N, ntiles);
        }
        transform_stats<<<1, 128, 0, stream>>>(st1, invN, g1, be1, ss1);
        // gemm2: lrelu(bn(xA)) @ w2 -> xA (in-place)
        gemm_mfma_kernel<128, true><<<GEMM_GRID, 256, 0, stream>>>(
            xA, ss1, w2, b2, xA, st2, N, ntiles);
        transform_stats<<<1, 128, 0, stream>>>(st2, invN, g2, be2, ss2);
        // bn+lrelu: xA -> xB  (x for next layer / final)
        int t4 = N * 32;
        bn_lrelu_kernel<<<(t4 + 255) / 256, 256, 0, stream>>>(xA, ss2, xB, t4);
    }
    pool_kernel<<<((N + 31) / 32 * 64 + 255) / 256, 256, 0, stream>>>(xB, batch, poolb, N);
    final_kernel<<<(N + 3) / 4, 256, 0, stream>>>(xB, poolb, batch, wf, bfp, out, N);
}

// Round 6
// 1486.580 us; speedup vs baseline: 6.1330x; 1.0183x over previous
//
#include <hip/hip_runtime.h>

#define GEMM_GRID 512
#define GNUM 4096   // num graphs (fixed in reference)

typedef __attribute__((ext_vector_type(8))) short short8_t;
typedef __attribute__((ext_vector_type(4))) float f32x4;

__device__ __forceinline__ float bf2f(unsigned short u) {
    union { unsigned int i; float f; } v; v.i = ((unsigned int)u) << 16; return v.f;
}
__device__ __forceinline__ unsigned short f2bf(float f) {
    union { float f; unsigned int i; } v; v.f = f;
    unsigned int b = v.i + 0x7FFFu + ((v.i >> 16) & 1u);
    return (unsigned short)(b >> 16);
}
__device__ __forceinline__ float lrelu(float v) { return v > 0.f ? v : 0.01f * v; }

// ================================================================ CSR build
__global__ __launch_bounds__(256) void hist_kernel(
    const int* __restrict__ dstv, int* __restrict__ cnt, int E)
{
    int i = blockIdx.x * 256 + threadIdx.x;
    if (i < E) atomicAdd(&cnt[dstv[i] + 1], 1);
}

__global__ __launch_bounds__(256) void scan_block_kernel(
    int* __restrict__ data, int* __restrict__ bsum, int n)
{
    __shared__ int s[256];
    int tid = threadIdx.x;
    int base = blockIdx.x * 1024 + tid * 4;
    int v[4]; int run = 0;
    #pragma unroll
    for (int i = 0; i < 4; i++) {
        int x = (base + i < n) ? data[base + i] : 0;
        run += x; v[i] = run;
    }
    s[tid] = run; __syncthreads();
    for (int off = 1; off < 256; off <<= 1) {
        int t = (tid >= off) ? s[tid - off] : 0;
        __syncthreads();
        s[tid] += t;
        __syncthreads();
    }
    int excl = s[tid] - run;
    #pragma unroll
    for (int i = 0; i < 4; i++)
        if (base + i < n) data[base + i] = v[i] + excl;
    if (tid == 255) bsum[blockIdx.x] = s[255];
}

__global__ __launch_bounds__(128) void scan_carry_kernel(int* __restrict__ bsum, int nb)
{
    __shared__ int s[128];
    int tid = threadIdx.x;
    int orig = (tid < nb) ? bsum[tid] : 0;
    s[tid] = orig; __syncthreads();
    for (int off = 1; off < 128; off <<= 1) {
        int t = (tid >= off) ? s[tid - off] : 0;
        __syncthreads();
        s[tid] += t;
        __syncthreads();
    }
    if (tid < nb) bsum[tid] = s[tid] - orig;
}

__global__ __launch_bounds__(256) void scan_add_kernel(
    int* __restrict__ data, const int* __restrict__ bsum,
    int* __restrict__ cursor, int n, int N)
{
    int i = blockIdx.x * 256 + threadIdx.x;
    if (i < n) {
        int v = data[i] + bsum[i >> 10];
        data[i] = v;
        if (i < N) cursor[i] = v;
    }
}

__global__ __launch_bounds__(256) void scatter_kernel(
    const int* __restrict__ dstv, int* __restrict__ cursor,
    int* __restrict__ perm, int E)
{
    int i = blockIdx.x * 256 + threadIdx.x;
    if (i < E) {
        int p = atomicAdd(&cursor[dstv[i]], 1);
        perm[p] = i;
    }
}

// ================================================================ reorder
__global__ __launch_bounds__(256) void reorder_kernel(
    const float* __restrict__ ea, const int* __restrict__ srcv,
    const int* __restrict__ perm, float* __restrict__ eap,
    int* __restrict__ srcp, int E)
{
    int i = blockIdx.x * 256 + threadIdx.x;
    int p = i >> 2, q = i & 3;
    if (p >= E) return;
    int e = perm[p];
    float4 v = reinterpret_cast<const float4*>(ea)[e * 4 + q];
    reinterpret_cast<float4*>(eap)[p * 4 + q] = v;
    if (q == 0) srcp[p] = srcv[e];
}

// ================================================================ gather, layer 0 (C=32, raw x0)
// half-wave per edge, 2 edges in flight per half (4 edges/iter).
template<bool RO>
__global__ __launch_bounds__(256) void gather_kernel32(
    const float* __restrict__ ea, const int* __restrict__ srcv,
    const int* __restrict__ perm, const int* __restrict__ off,
    const float* __restrict__ ew, const float* __restrict__ ebias,
    const float* __restrict__ epsp, const float* __restrict__ x,
    float* __restrict__ agg, int N)
{
    int lane = threadIdx.x & 63;
    int n = __builtin_amdgcn_readfirstlane((int)((blockIdx.x * 256 + threadIdx.x) >> 6));
    if (n >= N) return;
    const int h = lane >> 5;
    const int c = lane & 31;
    float ewr[16];
    #pragma unroll
    for (int k = 0; k < 16; k++) ewr[k] = ew[k * 32 + c];
    const float ebr = ebias[c];
    float acc = 0.f;
    const int p0 = off[n], end = off[n + 1];
    for (int p = p0; p < end; p += 4) {
        int pa = p + h, pb = p + 2 + h;
        bool va = pa < end, vb = pb < end;
        int ia = va ? pa : p;
        int ib = vb ? pb : p;
        int eA = RO ? ia : perm[ia];
        int eB = RO ? ib : perm[ib];
        int sa = srcv[eA], sb = srcv[eB];
        const float4* apA = reinterpret_cast<const float4*>(ea + (size_t)eA * 16);
        const float4* apB = reinterpret_cast<const float4*>(ea + (size_t)eB * 16);
        float av[16], bv[16];
        #pragma unroll
        for (int q = 0; q < 4; q++) {
            float4 t = apA[q]; av[4*q]=t.x; av[4*q+1]=t.y; av[4*q+2]=t.z; av[4*q+3]=t.w;
            float4 u = apB[q]; bv[4*q]=u.x; bv[4*q+1]=u.y; bv[4*q+2]=u.z; bv[4*q+3]=u.w;
        }
        float xa = x[(size_t)sa * 32 + c];
        float xb = x[(size_t)sb * 32 + c];
        float ua = ebr, ub = ebr;
        #pragma unroll
        for (int k = 0; k < 16; k++) {
            ua = fmaf(av[k], ewr[k], ua);
            ub = fmaf(bv[k], ewr[k], ub);
        }
        acc += va ? fmaxf(xa + ua, 0.f) : 0.f;
        acc += vb ? fmaxf(xb + ub, 0.f) : 0.f;
    }
    acc += __shfl_xor(acc, 32);
    if (lane < 32) {
        float s = 1.f + epsp[0];
        agg[(size_t)n * 32 + c] = fmaf(x[(size_t)n * 32 + c], s, acc);
    }
}

// ================================================================ gather, layers 1/2 (C=128)
// x input is the RAW gemm2 output U; BN(scale/shift from stats)+lrelu fused at load.
template<bool RO>
__global__ __launch_bounds__(256) void gather_kernel128_bn(
    const float* __restrict__ ea, const int* __restrict__ srcv,
    const int* __restrict__ perm, const int* __restrict__ off,
    const float* __restrict__ ew, const float* __restrict__ ebias,
    const float* __restrict__ epsp, const float* __restrict__ U,
    const float* __restrict__ stats, const float* __restrict__ g,
    const float* __restrict__ be, float invN,
    float* __restrict__ agg, int N)
{
    int lane = threadIdx.x & 63;
    int n = __builtin_amdgcn_readfirstlane((int)((blockIdx.x * 256 + threadIdx.x) >> 6));
    if (n >= N) return;
    const int c0 = lane * 2;
    // BN params for this lane's two channels
    float sc0, sh0, sc1, sh1;
    {
        float m0 = stats[c0] * invN;
        float v0 = fmaxf(stats[128 + c0] * invN - m0 * m0, 0.f);
        sc0 = g[c0] * rsqrtf(v0 + 1e-5f);
        sh0 = be[c0] - m0 * sc0;
        float m1 = stats[c0 + 1] * invN;
        float v1 = fmaxf(stats[128 + c0 + 1] * invN - m1 * m1, 0.f);
        sc1 = g[c0 + 1] * rsqrtf(v1 + 1e-5f);
        sh1 = be[c0 + 1] - m1 * sc1;
    }
    float ew0[16], ew1[16];
    #pragma unroll
    for (int k = 0; k < 16; k++) {
        float2 w = *reinterpret_cast<const float2*>(&ew[k * 128 + c0]);
        ew0[k] = w.x; ew1[k] = w.y;
    }
    const float eb0 = ebias[c0], eb1 = ebias[c0 + 1];
    float acc0 = 0.f, acc1 = 0.f;
    int p = off[n];
    const int end = off[n + 1];
    for (; p + 2 <= end; p += 2) {
        int e0 = RO ? p : perm[p];
        int e1 = RO ? (p + 1) : perm[p + 1];
        int s0 = srcv[e0], s1 = srcv[e1];
        const float4* ap0 = reinterpret_cast<const float4*>(ea + (size_t)e0 * 16);
        const float4* ap1 = reinterpret_cast<const float4*>(ea + (size_t)e1 * 16);
        float av[16], bv[16];
        #pragma unroll
        for (int q = 0; q < 4; q++) {
            float4 t = ap0[q]; av[4*q]=t.x; av[4*q+1]=t.y; av[4*q+2]=t.z; av[4*q+3]=t.w;
            float4 u = ap1[q]; bv[4*q]=u.x; bv[4*q+1]=u.y; bv[4*q+2]=u.z; bv[4*q+3]=u.w;
        }
        float2 xv0 = *reinterpret_cast<const float2*>(&U[(size_t)s0 * 128 + c0]);
        float2 xv1 = *reinterpret_cast<const float2*>(&U[(size_t)s1 * 128 + c0]);
        float x00 = lrelu(fmaf(xv0.x, sc0, sh0));
        float x01 = lrelu(fmaf(xv0.y, sc1, sh1));
        float x10 = lrelu(fmaf(xv1.x, sc0, sh0));
        float x11 = lrelu(fmaf(xv1.y, sc1, sh1));
        float u0 = eb0, u1 = eb1, w0 = eb0, w1 = eb1;
        #pragma unroll
        for (int k = 0; k < 16; k++) {
            u0 = fmaf(av[k], ew0[k], u0);
            u1 = fmaf(av[k], ew1[k], u1);
            w0 = fmaf(bv[k], ew0[k], w0);
            w1 = fmaf(bv[k], ew1[k], w1);
        }
        acc0 += fmaxf(x00 + u0, 0.f) + fmaxf(x10 + w0, 0.f);
        acc1 += fmaxf(x01 + u1, 0.f) + fmaxf(x11 + w1, 0.f);
    }
    if (p < end) {
        int e0 = RO ? p : perm[p];
        int s0 = srcv[e0];
        const float4* ap0 = reinterpret_cast<const float4*>(ea + (size_t)e0 * 16);
        float av[16];
        #pragma unroll
        for (int q = 0; q < 4; q++) {
            float4 t = ap0[q]; av[4*q]=t.x; av[4*q+1]=t.y; av[4*q+2]=t.z; av[4*q+3]=t.w;
        }
        float2 xv0 = *reinterpret_cast<const float2*>(&U[(size_t)s0 * 128 + c0]);
        float x00 = lrelu(fmaf(xv0.x, sc0, sh0));
        float x01 = lrelu(fmaf(xv0.y, sc1, sh1));
        float u0 = eb0, u1 = eb1;
        #pragma unroll
        for (int k = 0; k < 16; k++) {
            u0 = fmaf(av[k], ew0[k], u0);
            u1 = fmaf(av[k], ew1[k], u1);
        }
        acc0 += fmaxf(x00 + u0, 0.f);
        acc1 += fmaxf(x01 + u1, 0.f);
    }
    float2 xn = *reinterpret_cast<const float2*>(&U[(size_t)n * 128 + c0]);
    float xn0 = lrelu(fmaf(xn.x, sc0, sh0));
    float xn1 = lrelu(fmaf(xn.y, sc1, sh1));
    float s = 1.f + epsp[0];
    float2 o;
    o.x = fmaf(xn0, s, acc0);
    o.y = fmaf(xn1, s, acc1);
    *reinterpret_cast<float2*>(&agg[(size_t)n * 128 + c0]) = o;
}

// ================================================================ MFMA GEMM (split-A) + BN stats
// out[N,128] = f(A)[N,K] @ W[K,128] + bias; W bf16(RNE); A split hi/lo by
// TRUNCATION (v_perm packing, cheap). f = identity or lrelu(bn(.)) with BN
// params computed in-kernel from raw stats_in. In-place safe (out==A).
// Column sum/sumsq of out -> stats_out via end-of-kernel atomics.
template<int K, bool BN_IN>
__global__ __launch_bounds__(256, 3) void gemm_mfma_kernel(
    const float* __restrict__ A,
    const float* __restrict__ stats_in, const float* __restrict__ g,
    const float* __restrict__ be, float invN,
    const float* __restrict__ W, const float* __restrict__ bias,
    float* __restrict__ out, float* __restrict__ stats_out, int N, int ntiles)
{
    constexpr int PA = K + 8;                  // LDS pitch in bf16 elems
    __shared__ unsigned short As_hi[32 * PA];
    __shared__ unsigned short As_lo[32 * PA];
    __shared__ unsigned short Wt[128 * PA];    // Wt[n][k]
    __shared__ float scale_s[K];
    __shared__ float shift_s[K];
    const int tid = threadIdx.x;
    const int w = tid >> 6;
    const int lane = tid & 63;
    const int quad = lane >> 4;
    const int l16 = lane & 15;
    const int rbase = (w & 1) * 16;
    const int nbase = (w >> 1) * 4;

    for (int idx = tid; idx < K * 128; idx += 256) {
        int k = idx >> 7, nn = idx & 127;
        Wt[nn * PA + k] = f2bf(W[idx]);
    }
    if (BN_IN) {
        for (int i = tid; i < K; i += 256) {
            float m = stats_in[i] * invN;
            float va = fmaxf(stats_in[K + i] * invN - m * m, 0.f);
            float sc = g[i] * rsqrtf(va + 1e-5f);
            scale_s[i] = sc;
            shift_s[i] = be[i] - m * sc;
        }
    }
    float bcol[4];
    #pragma unroll
    for (int nt = 0; nt < 4; nt++) bcol[nt] = bias[(nbase + nt) * 16 + l16];
    float csum[4] = {0.f, 0.f, 0.f, 0.f}, csq[4] = {0.f, 0.f, 0.f, 0.f};

    constexpr int C8 = K / 8;

    for (int tile = blockIdx.x; tile < ntiles; tile += gridDim.x) {
        const int row0 = tile * 32;
        __syncthreads();
        for (int cid = tid; cid < 32 * C8; cid += 256) {
            int row = cid / C8, c8 = cid % C8;
            int r = row0 + row;
            float f[8];
            if (r < N) {
                float4 u0 = *reinterpret_cast<const float4*>(&A[(size_t)r * K + c8 * 8]);
                float4 u1 = *reinterpret_cast<const float4*>(&A[(size_t)r * K + c8 * 8 + 4]);
                f[0]=u0.x; f[1]=u0.y; f[2]=u0.z; f[3]=u0.w;
                f[4]=u1.x; f[5]=u1.y; f[6]=u1.z; f[7]=u1.w;
            } else {
                #pragma unroll
                for (int j = 0; j < 8; j++) f[j] = 0.f;
            }
            if (BN_IN) {
                int kb = c8 * 8;
                #pragma unroll
                for (int j = 0; j < 8; j++)
                    f[j] = lrelu(fmaf(f[j], scale_s[kb + j], shift_s[kb + j]));
            }
            unsigned int hi[4], lo[4];
            #pragma unroll
            for (int j = 0; j < 4; j++) {
                unsigned int b0 = __float_as_uint(f[2*j]);
                unsigned int b1 = __float_as_uint(f[2*j + 1]);
                hi[j] = __builtin_amdgcn_perm(b1, b0, 0x07060302u);   // {top16(b1),top16(b0)}
                float l0 = f[2*j]     - __uint_as_float(b0 & 0xffff0000u);
                float l1 = f[2*j + 1] - __uint_as_float(b1 & 0xffff0000u);
                lo[j] = __builtin_amdgcn_perm(__float_as_uint(l1), __float_as_uint(l0), 0x07060302u);
            }
            *reinterpret_cast<uint4*>(&As_hi[row * PA + c8 * 8]) = make_uint4(hi[0], hi[1], hi[2], hi[3]);
            *reinterpret_cast<uint4*>(&As_lo[row * PA + c8 * 8]) = make_uint4(lo[0], lo[1], lo[2], lo[3]);
        }
        __syncthreads();

        f32x4 acc[4];
        #pragma unroll
        for (int nt = 0; nt < 4; nt++) { f32x4 z = {0.f,0.f,0.f,0.f}; acc[nt] = z; }
        #pragma unroll
        for (int chunk = 0; chunk < K / 32; chunk++) {
            short8_t ahi = *reinterpret_cast<const short8_t*>(
                &As_hi[(rbase + l16) * PA + chunk * 32 + quad * 8]);
            short8_t alo = *reinterpret_cast<const short8_t*>(
                &As_lo[(rbase + l16) * PA + chunk * 32 + quad * 8]);
            #pragma unroll
            for (int nt = 0; nt < 4; nt++) {
                short8_t bfr = *reinterpret_cast<const short8_t*>(
                    &Wt[((nbase + nt) * 16 + l16) * PA + chunk * 32 + quad * 8]);
                acc[nt] = __builtin_amdgcn_mfma_f32_16x16x32_bf16(alo, bfr, acc[nt], 0, 0, 0);
                acc[nt] = __builtin_amdgcn_mfma_f32_16x16x32_bf16(ahi, bfr, acc[nt], 0, 0, 0);
            }
        }
        const int rb = row0 + rbase + quad * 4;
        #pragma unroll
        for (int nt = 0; nt < 4; nt++) {
            #pragma unroll
            for (int rg = 0; rg < 4; rg++) {
                int r = rb + rg;
                if (r < N) {
                    float v = acc[nt][rg] + bcol[nt];
                    out[(size_t)r * 128 + (nbase + nt) * 16 + l16] = v;
                    csum[nt] += v; csq[nt] += v * v;
                }
            }
        }
    }
    #pragma unroll
    for (int nt = 0; nt < 4; nt++) {
        float s = csum[nt]; s += __shfl_xor(s, 16); s += __shfl_xor(s, 32);
        float q = csq[nt];  q += __shfl_xor(q, 16); q += __shfl_xor(q, 32);
        if (quad == 0) {
            int col = (nbase + nt) * 16 + l16;
            atomicAdd(&stats_out[col], s);
            atomicAdd(&stats_out[128 + col], q);
        }
    }
}

// ================================================================ global add pool (BN fused)
__global__ __launch_bounds__(256) void pool_kernel_bn(
    const float* __restrict__ U, const int* __restrict__ batch,
    const float* __restrict__ stats, const float* __restrict__ g,
    const float* __restrict__ be, float invN,
    float* __restrict__ pool, int N)
{
    int w = (blockIdx.x * 256 + threadIdx.x) >> 6;
    int lane = threadIdx.x & 63;
    int n0 = w * 32;
    if (n0 >= N) return;
    int n1 = min(n0 + 32, N);
    int c0 = lane * 2;
    float sc0, sh0, sc1, sh1;
    {
        float m0 = stats[c0] * invN;
        float v0 = fmaxf(stats[128 + c0] * invN - m0 * m0, 0.f);
        sc0 = g[c0] * rsqrtf(v0 + 1e-5f);
        sh0 = be[c0] - m0 * sc0;
        float m1 = stats[c0 + 1] * invN;
        float v1 = fmaxf(stats[128 + c0 + 1] * invN - m1 * m1, 0.f);
        sc1 = g[c0 + 1] * rsqrtf(v1 + 1e-5f);
        sh1 = be[c0 + 1] - m1 * sc1;
    }
    float a0 = 0.f, a1 = 0.f;
    int cur = batch[n0];
    for (int n = n0; n < n1; ++n) {
        int b = batch[n];
        if (b != cur) {
            atomicAdd(&pool[(size_t)cur * 128 + c0], a0);
            atomicAdd(&pool[(size_t)cur * 128 + c0 + 1], a1);
            a0 = a1 = 0.f; cur = b;
        }
        float2 v = *reinterpret_cast<const float2*>(&U[(size_t)n * 128 + c0]);
        a0 += lrelu(fmaf(v.x, sc0, sh0));
        a1 += lrelu(fmaf(v.y, sc1, sh1));
    }
    atomicAdd(&pool[(size_t)cur * 128 + c0], a0);
    atomicAdd(&pool[(size_t)cur * 128 + c0 + 1], a1);
}

// ================================================================ final (BN fused)
__global__ __launch_bounds__(256) void final_kernel_bn(
    const float* __restrict__ U, const float* __restrict__ pool,
    const int* __restrict__ batch,
    const float* __restrict__ stats, const float* __restrict__ g,
    const float* __restrict__ be, float invN,
    const float* __restrict__ wf, const float* __restrict__ bf,
    float* __restrict__ out, int N)
{
    __shared__ float wf_s[512];
    int tid = threadIdx.x;
    for (int i = tid; i < 512; i += 256) wf_s[i] = wf[i];
    __syncthreads();
    int wid = tid >> 6, lane = tid & 63;
    int n = blockIdx.x * 4 + wid;
    if (n >= N) return;
    int cA = lane, cB = 64 + lane;
    float scA, shA, scB, shB;
    {
        float mA = stats[cA] * invN;
        float vA = fmaxf(stats[128 + cA] * invN - mA * mA, 0.f);
        scA = g[cA] * rsqrtf(vA + 1e-5f);
        shA = be[cA] - mA * scA;
        float mB = stats[cB] * invN;
        float vB = fmaxf(stats[128 + cB] * invN - mB * mB, 0.f);
        scB = g[cB] * rsqrtf(vB + 1e-5f);
        shB = be[cB] - mB * scB;
    }
    int b = batch[n];
    float v0 = lrelu(fmaf(U[(size_t)n * 128 + cA], scA, shA));
    float v1 = lrelu(fmaf(U[(size_t)n * 128 + cB], scB, shB));
    float p0 = pool[(size_t)b * 128 + cA];
    float p1 = pool[(size_t)b * 128 + cB];
    float a0 = v0 * wf_s[lane * 2]       + v1 * wf_s[(64 + lane) * 2]
             + p0 * wf_s[(128 + lane) * 2] + p1 * wf_s[(192 + lane) * 2];
    float a1 = v0 * wf_s[lane * 2 + 1]       + v1 * wf_s[(64 + lane) * 2 + 1]
             + p0 * wf_s[(128 + lane) * 2 + 1] + p1 * wf_s[(192 + lane) * 2 + 1];
    #pragma unroll
    for (int off = 32; off >= 1; off >>= 1) {
        a0 += __shfl_down(a0, off);
        a1 += __shfl_down(a1, off);
    }
    if (lane == 0) {
        a0 += bf[0]; a1 += bf[1];
        float mx = fmaxf(a0, a1);
        float e0 = __expf(a0 - mx), e1 = __expf(a1 - mx);
        float inv = 1.f / (e0 + e1);
        out[(size_t)n * 2]     = e0 * inv;
        out[(size_t)n * 2 + 1] = e1 * inv;
    }
}

// ================================================================ launch
extern "C" void kernel_launch(void* const* d_in, const int* in_sizes, int n_in,
                              void* d_out, int out_size, void* d_ws, size_t ws_size,
                              hipStream_t stream)
{
    const float* x0    = (const float*)d_in[0];
    const int*   ei    = (const int*)d_in[1];
    const float* ea    = (const float*)d_in[2];
    const int*   batch = (const int*)d_in[3];
    const int E = in_sizes[1] / 2;
    const int N = in_sizes[3];
    const int* srcv = ei;
    const int* dstv = ei + E;
    const float* wf = (const float*)d_in[37];
    const float* bfp = (const float*)d_in[38];
    float* out = (float*)d_out;
    const float invN = 1.0f / (float)N;
    const int ntiles = (N + 31) / 32;

    // ---- workspace layout (floats) ----
    const size_t base_f = (size_t)2 * N * 128 + (size_t)GNUM * 128 + 6 * 256
                        + (size_t)(N + 1) + (size_t)N + 128 + (size_t)E;
    const size_t full_f = base_f + (size_t)E * 16 + (size_t)E;
    const bool ro = (ws_size >= full_f * 4);

    float* ws = (float*)d_ws;
    size_t o = 0;
    float* xA    = ws + o; o += (size_t)N * 128;
    float* xB    = ws + o; o += (size_t)N * 128;
    float* eap   = ws + o; o += ro ? (size_t)E * 16 : 0;
    float* poolb = ws + o; o += (size_t)GNUM * 128;
    float* statsb= ws + o; o += 6 * 256;
    int* srcp    = (int*)(ws + o); o += ro ? (size_t)E : 0;
    int* off     = (int*)(ws + o); o += (size_t)(N + 1);
    int* cursor  = (int*)(ws + o); o += (size_t)N;
    int* bsumb   = (int*)(ws + o); o += 128;
    int* perm    = (int*)(ws + o);

    // ---- CSR build (by destination) ----
    hipMemsetAsync(off, 0, (size_t)(N + 1) * sizeof(int), stream);
    hipMemsetAsync(statsb, 0, (size_t)6 * 256 * sizeof(float), stream);
    hipMemsetAsync(poolb, 0, (size_t)GNUM * 128 * sizeof(float), stream);
    hist_kernel<<<(E + 255) / 256, 256, 0, stream>>>(dstv, off, E);
    const int n1 = N + 1;
    const int nb = (n1 + 1023) / 1024;
    scan_block_kernel<<<nb, 256, 0, stream>>>(off, bsumb, n1);
    scan_carry_kernel<<<1, 128, 0, stream>>>(bsumb, nb);
    scan_add_kernel<<<(n1 + 255) / 256, 256, 0, stream>>>(off, bsumb, cursor, n1, N);
    scatter_kernel<<<(E + 255) / 256, 256, 0, stream>>>(dstv, cursor, perm, E);
    if (ro)
        reorder_kernel<<<(E * 4 + 255) / 256, 256, 0, stream>>>(ea, srcv, perm, eap, srcp, E);

    const float* g_ea  = ro ? eap  : ea;
    const int*   g_src = ro ? srcp : srcv;
    const int gather_blocks = (N + 3) / 4;

    // U-buffer of previous layer and its BN params (for gather/pool/final)
    float* Uprev = nullptr;
    const float *pg = nullptr, *pbe = nullptr;
    float* pstats = nullptr;

    for (int l = 0; l < 3; l++) {
        const int C = (l == 0) ? 32 : 128;
        int bidx = 4 + l * 11;
        const float* epsp = (const float*)d_in[bidx + 0];
        const float* ew   = (const float*)d_in[bidx + 1];
        const float* eb   = (const float*)d_in[bidx + 2];
        const float* w1   = (const float*)d_in[bidx + 3];
        const float* b1   = (const float*)d_in[bidx + 4];
        const float* g1   = (const float*)d_in[bidx + 5];
        const float* be1  = (const float*)d_in[bidx + 6];
        const float* w2   = (const float*)d_in[bidx + 7];
        const float* b2   = (const float*)d_in[bidx + 8];
        const float* g2   = (const float*)d_in[bidx + 9];
        const float* be2  = (const float*)d_in[bidx + 10];
        float* st1 = statsb + (size_t)(l * 2) * 256;
        float* st2 = statsb + (size_t)(l * 2 + 1) * 256;

        if (l == 0) {
            // gather32: x0 -> xB[N,32]; gemm1: xB -> xA; gemm2: xA -> xA
            if (ro) gather_kernel32<true><<<gather_blocks, 256, 0, stream>>>(
                        g_ea, g_src, perm, off, ew, eb, epsp, x0, xB, N);
            else    gather_kernel32<false><<<gather_blocks, 256, 0, stream>>>(
                        g_ea, g_src, perm, off, ew, eb, epsp, x0, xB, N);
            gemm_mfma_kernel<32, false><<<GEMM_GRID, 256, 0, stream>>>(
                xB, nullptr, nullptr, nullptr, invN, w1, b1, xA, st1, N, ntiles);
            gemm_mfma_kernel<128, true><<<GEMM_GRID, 256, 0, stream>>>(
                xA, st1, g1, be1, invN, w2, b2, xA, st2, N, ntiles);
            Uprev = xA;
        } else {
            // gather128_bn: Uprev(+BN) -> other buffer; gemms in-place there
            float* dst = (Uprev == xA) ? xB : xA;
            if (ro) gather_kernel128_bn<true><<<gather_blocks, 256, 0, stream>>>(
                        g_ea, g_src, perm, off, ew, eb, epsp, Uprev,
                        pstats, pg, pbe, invN, dst, N);
            else    gather_kernel128_bn<false><<<gather_blocks, 256, 0, stream>>>(
                        g_ea, g_src, perm, off, ew, eb, epsp, Uprev,
                        pstats, pg, pbe, invN, dst, N);
            gemm_mfma_kernel<128, false><<<GEMM_GRID, 256, 0, stream>>>(
                dst, nullptr, nullptr, nullptr, invN, w1, b1, dst, st1, N, ntiles);
            gemm_mfma_kernel<128, true><<<GEMM_GRID, 256, 0, stream>>>(
                dst, st1, g1, be1, invN, w2, b2, dst, st2, N, ntiles);
            Uprev = dst;
        }
        pstats = st2; pg = g2; pbe = be2;
    }
    pool_kernel_bn<<<((N + 31) / 32 * 64 + 255) / 256, 256, 0, stream>>>(
        Uprev, batch, pstats, pg, pbe, invN, poolb, N);
    final_kernel_bn<<<(N + 3) / 4, 256, 0, stream>>>(
        Uprev, poolb, batch, pstats, pg, pbe, invN, wf, bfp, out, N);
}

// Round 7
// 1458.049 us; speedup vs baseline: 6.2530x; 1.0196x over previous
//
#include <hip/hip_runtime.h>

#define GEMM_GRID 512
#define GNUM 4096   // num graphs (fixed in reference)

typedef __attribute__((ext_vector_type(8))) short short8_t;
typedef __attribute__((ext_vector_type(4))) float f32x4;
typedef __attribute__((ext_vector_type(2))) float v2f;

__device__ __forceinline__ float bf2f(unsigned short u) {
    union { unsigned int i; float f; } v; v.i = ((unsigned int)u) << 16; return v.f;
}
__device__ __forceinline__ unsigned short f2bf(float f) {
    union { float f; unsigned int i; } v; v.f = f;
    unsigned int b = v.i + 0x7FFFu + ((v.i >> 16) & 1u);
    return (unsigned short)(b >> 16);
}
__device__ __forceinline__ float lrelu(float v) { return v > 0.f ? v : 0.01f * v; }

// ================================================================ CSR build
__global__ __launch_bounds__(256) void hist_kernel(
    const int* __restrict__ dstv, int* __restrict__ cnt, int E)
{
    int i = blockIdx.x * 256 + threadIdx.x;
    if (i < E) atomicAdd(&cnt[dstv[i] + 1], 1);
}

__global__ __launch_bounds__(256) void scan_block_kernel(
    int* __restrict__ data, int* __restrict__ bsum, int n)
{
    __shared__ int s[256];
    int tid = threadIdx.x;
    int base = blockIdx.x * 1024 + tid * 4;
    int v[4]; int run = 0;
    #pragma unroll
    for (int i = 0; i < 4; i++) {
        int x = (base + i < n) ? data[base + i] : 0;
        run += x; v[i] = run;
    }
    s[tid] = run; __syncthreads();
    for (int off = 1; off < 256; off <<= 1) {
        int t = (tid >= off) ? s[tid - off] : 0;
        __syncthreads();
        s[tid] += t;
        __syncthreads();
    }
    int excl = s[tid] - run;
    #pragma unroll
    for (int i = 0; i < 4; i++)
        if (base + i < n) data[base + i] = v[i] + excl;
    if (tid == 255) bsum[blockIdx.x] = s[255];
}

__global__ __launch_bounds__(128) void scan_carry_kernel(int* __restrict__ bsum, int nb)
{
    __shared__ int s[128];
    int tid = threadIdx.x;
    int orig = (tid < nb) ? bsum[tid] : 0;
    s[tid] = orig; __syncthreads();
    for (int off = 1; off < 128; off <<= 1) {
        int t = (tid >= off) ? s[tid - off] : 0;
        __syncthreads();
        s[tid] += t;
        __syncthreads();
    }
    if (tid < nb) bsum[tid] = s[tid] - orig;
}

__global__ __launch_bounds__(256) void scan_add_kernel(
    int* __restrict__ data, const int* __restrict__ bsum,
    int* __restrict__ cursor, int n, int N)
{
    int i = blockIdx.x * 256 + threadIdx.x;
    if (i < n) {
        int v = data[i] + bsum[i >> 10];
        data[i] = v;
        if (i < N) cursor[i] = v;
    }
}

__global__ __launch_bounds__(256) void scatter_kernel(
    const int* __restrict__ dstv, int* __restrict__ cursor,
    int* __restrict__ perm, int E)
{
    int i = blockIdx.x * 256 + threadIdx.x;
    if (i < E) {
        int p = atomicAdd(&cursor[dstv[i]], 1);
        perm[p] = i;
    }
}

// ================================================================ reorder
__global__ __launch_bounds__(256) void reorder_kernel(
    const float* __restrict__ ea, const int* __restrict__ srcv,
    const int* __restrict__ perm, float* __restrict__ eap,
    int* __restrict__ srcp, int E)
{
    int i = blockIdx.x * 256 + threadIdx.x;
    int p = i >> 2, q = i & 3;
    if (p >= E) return;
    int e = perm[p];
    float4 v = reinterpret_cast<const float4*>(ea)[e * 4 + q];
    reinterpret_cast<float4*>(eap)[p * 4 + q] = v;
    if (q == 0) srcp[p] = srcv[e];
}

// ================================================================ gather, layer 0 (C=32, raw x0)
// Writes split bf16 hi/lo planes for copy-staged MFMA GEMM.
template<bool RO>
__global__ __launch_bounds__(256) void gather_kernel32(
    const float* __restrict__ ea, const int* __restrict__ srcv,
    const int* __restrict__ perm, const int* __restrict__ off,
    const float* __restrict__ ew, const float* __restrict__ ebias,
    const float* __restrict__ epsp, const float* __restrict__ x,
    unsigned short* __restrict__ aggh, unsigned short* __restrict__ aggl, int N)
{
    int lane = threadIdx.x & 63;
    int n = __builtin_amdgcn_readfirstlane((int)((blockIdx.x * 256 + threadIdx.x) >> 6));
    if (n >= N) return;
    const int h = lane >> 5;
    const int c = lane & 31;
    float ewr[16];
    #pragma unroll
    for (int k = 0; k < 16; k++) ewr[k] = ew[k * 32 + c];
    const float ebr = ebias[c];
    float acc = 0.f;
    const int p0 = off[n], end = off[n + 1];
    for (int p = p0; p < end; p += 4) {
        int pa = p + h, pb = p + 2 + h;
        bool va = pa < end, vb = pb < end;
        int ia = va ? pa : p;
        int ib = vb ? pb : p;
        int eA = RO ? ia : perm[ia];
        int eB = RO ? ib : perm[ib];
        int sa = srcv[eA], sb = srcv[eB];
        const float4* apA = reinterpret_cast<const float4*>(ea + (size_t)eA * 16);
        const float4* apB = reinterpret_cast<const float4*>(ea + (size_t)eB * 16);
        float av[16], bv[16];
        #pragma unroll
        for (int q = 0; q < 4; q++) {
            float4 t = apA[q]; av[4*q]=t.x; av[4*q+1]=t.y; av[4*q+2]=t.z; av[4*q+3]=t.w;
            float4 u = apB[q]; bv[4*q]=u.x; bv[4*q+1]=u.y; bv[4*q+2]=u.z; bv[4*q+3]=u.w;
        }
        float xa = x[(size_t)sa * 32 + c];
        float xb = x[(size_t)sb * 32 + c];
        float ua = ebr, ub = ebr;
        #pragma unroll
        for (int k = 0; k < 16; k++) {
            ua = fmaf(av[k], ewr[k], ua);
            ub = fmaf(bv[k], ewr[k], ub);
        }
        acc += va ? fmaxf(xa + ua, 0.f) : 0.f;
        acc += vb ? fmaxf(xb + ub, 0.f) : 0.f;
    }
    acc += __shfl_xor(acc, 32);
    if (lane < 32) {
        float s = 1.f + epsp[0];
        float f = fmaf(x[(size_t)n * 32 + c], s, acc);
        unsigned int b = __float_as_uint(f);
        unsigned short hi = (unsigned short)(b >> 16);
        float lo = f - __uint_as_float(b & 0xffff0000u);
        aggh[(size_t)n * 32 + c] = hi;
        aggl[(size_t)n * 32 + c] = f2bf(lo);
    }
}

// ================================================================ gather, layers 1/2 (C=128)
// Reads RAW gemm2 output U, fuses BN+lrelu at load (packed fp32 math),
// writes split bf16 hi/lo planes.
template<bool RO>
__global__ __launch_bounds__(256) void gather_kernel128_bn(
    const float* __restrict__ ea, const int* __restrict__ srcv,
    const int* __restrict__ perm, const int* __restrict__ off,
    const float* __restrict__ ew, const float* __restrict__ ebias,
    const float* __restrict__ epsp, const float* __restrict__ U,
    const float* __restrict__ stats, const float* __restrict__ g,
    const float* __restrict__ be, float invN,
    unsigned short* __restrict__ aggh, unsigned short* __restrict__ aggl, int N)
{
    int lane = threadIdx.x & 63;
    int n = __builtin_amdgcn_readfirstlane((int)((blockIdx.x * 256 + threadIdx.x) >> 6));
    if (n >= N) return;
    const int c0 = lane * 2;
    v2f scv, shv;
    {
        float m0 = stats[c0] * invN;
        float v0 = fmaxf(stats[128 + c0] * invN - m0 * m0, 0.f);
        scv.x = g[c0] * rsqrtf(v0 + 1e-5f);
        shv.x = be[c0] - m0 * scv.x;
        float m1 = stats[c0 + 1] * invN;
        float v1 = fmaxf(stats[128 + c0 + 1] * invN - m1 * m1, 0.f);
        scv.y = g[c0 + 1] * rsqrtf(v1 + 1e-5f);
        shv.y = be[c0 + 1] - m1 * scv.y;
    }
    v2f ewv[16];
    #pragma unroll
    for (int k = 0; k < 16; k++)
        ewv[k] = *reinterpret_cast<const v2f*>(&ew[k * 128 + c0]);
    const v2f ebv = *reinterpret_cast<const v2f*>(&ebias[c0]);
    v2f acc = {0.f, 0.f};
    int p = off[n];
    const int end = off[n + 1];
    for (; p + 2 <= end; p += 2) {
        int e0 = RO ? p : perm[p];
        int e1 = RO ? (p + 1) : perm[p + 1];
        int s0 = srcv[e0], s1 = srcv[e1];
        const float4* ap0 = reinterpret_cast<const float4*>(ea + (size_t)e0 * 16);
        const float4* ap1 = reinterpret_cast<const float4*>(ea + (size_t)e1 * 16);
        float av[16], bv[16];
        #pragma unroll
        for (int q = 0; q < 4; q++) {
            float4 t = ap0[q]; av[4*q]=t.x; av[4*q+1]=t.y; av[4*q+2]=t.z; av[4*q+3]=t.w;
            float4 u = ap1[q]; bv[4*q]=u.x; bv[4*q+1]=u.y; bv[4*q+2]=u.z; bv[4*q+3]=u.w;
        }
        v2f xv0 = *reinterpret_cast<const v2f*>(&U[(size_t)s0 * 128 + c0]);
        v2f xv1 = *reinterpret_cast<const v2f*>(&U[(size_t)s1 * 128 + c0]);
        v2f x0b = xv0 * scv + shv;
        v2f x1b = xv1 * scv + shv;
        x0b.x = lrelu(x0b.x); x0b.y = lrelu(x0b.y);
        x1b.x = lrelu(x1b.x); x1b.y = lrelu(x1b.y);
        v2f u = ebv, w = ebv;
        #pragma unroll
        for (int k = 0; k < 16; k++) {
            u = ewv[k] * av[k] + u;
            w = ewv[k] * bv[k] + w;
        }
        v2f m0 = x0b + u, m1 = x1b + w;
        m0.x = fmaxf(m0.x, 0.f); m0.y = fmaxf(m0.y, 0.f);
        m1.x = fmaxf(m1.x, 0.f); m1.y = fmaxf(m1.y, 0.f);
        acc = acc + m0 + m1;
    }
    if (p < end) {
        int e0 = RO ? p : perm[p];
        int s0 = srcv[e0];
        const float4* ap0 = reinterpret_cast<const float4*>(ea + (size_t)e0 * 16);
        float av[16];
        #pragma unroll
        for (int q = 0; q < 4; q++) {
            float4 t = ap0[q]; av[4*q]=t.x; av[4*q+1]=t.y; av[4*q+2]=t.z; av[4*q+3]=t.w;
        }
        v2f xv0 = *reinterpret_cast<const v2f*>(&U[(size_t)s0 * 128 + c0]);
        v2f x0b = xv0 * scv + shv;
        x0b.x = lrelu(x0b.x); x0b.y = lrelu(x0b.y);
        v2f u = ebv;
        #pragma unroll
        for (int k = 0; k < 16; k++) u = ewv[k] * av[k] + u;
        v2f m0 = x0b + u;
        m0.x = fmaxf(m0.x, 0.f); m0.y = fmaxf(m0.y, 0.f);
        acc = acc + m0;
    }
    v2f xn = *reinterpret_cast<const v2f*>(&U[(size_t)n * 128 + c0]);
    v2f xnb = xn * scv + shv;
    xnb.x = lrelu(xnb.x); xnb.y = lrelu(xnb.y);
    float s = 1.f + epsp[0];
    v2f o = xnb * s + acc;
    // split-pack: hi = trunc-top16, lo = residual (RNE)
    unsigned int b0 = __float_as_uint(o.x);
    unsigned int b1 = __float_as_uint(o.y);
    unsigned int hp = __builtin_amdgcn_perm(b1, b0, 0x07060302u);
    float l0 = o.x - __uint_as_float(b0 & 0xffff0000u);
    float l1 = o.y - __uint_as_float(b1 & 0xffff0000u);
    unsigned int lp = (unsigned int)f2bf(l0) | ((unsigned int)f2bf(l1) << 16);
    *reinterpret_cast<unsigned int*>(&aggh[(size_t)n * 128 + c0]) = hp;
    *reinterpret_cast<unsigned int*>(&aggl[(size_t)n * 128 + c0]) = lp;
}

// ================================================================ MFMA GEMM, copy-staged (pre-split A)
// out[N,128](fp32) = A @ W + bias; A given as bf16 hi/lo planes.
// Staging is a pure uint4 copy. Column sum/sumsq -> stats_out atomics.
template<int K>
__global__ __launch_bounds__(256, 3) void gemm_copy_mfma_kernel(
    const unsigned short* __restrict__ Ah, const unsigned short* __restrict__ Al,
    const float* __restrict__ W, const float* __restrict__ bias,
    float* __restrict__ out, float* __restrict__ stats_out, int N, int ntiles)
{
    constexpr int PA = K + 8;
    __shared__ unsigned short As_hi[32 * PA];
    __shared__ unsigned short As_lo[32 * PA];
    __shared__ unsigned short Wt[128 * PA];
    const int tid = threadIdx.x;
    const int w = tid >> 6;
    const int lane = tid & 63;
    const int quad = lane >> 4;
    const int l16 = lane & 15;
    const int rbase = (w & 1) * 16;
    const int nbase = (w >> 1) * 4;

    for (int idx = tid; idx < K * 128; idx += 256) {
        int k = idx >> 7, nn = idx & 127;
        Wt[nn * PA + k] = f2bf(W[idx]);
    }
    float bcol[4];
    #pragma unroll
    for (int nt = 0; nt < 4; nt++) bcol[nt] = bias[(nbase + nt) * 16 + l16];
    float csum[4] = {0.f, 0.f, 0.f, 0.f}, csq[4] = {0.f, 0.f, 0.f, 0.f};

    constexpr int C8 = K / 8;

    for (int tile = blockIdx.x; tile < ntiles; tile += gridDim.x) {
        const int row0 = tile * 32;
        __syncthreads();
        for (int cid = tid; cid < 32 * C8; cid += 256) {
            int row = cid / C8, c8 = cid % C8;
            int r = row0 + row;
            uint4 h, l;
            if (r < N) {
                h = *reinterpret_cast<const uint4*>(&Ah[(size_t)r * K + c8 * 8]);
                l = *reinterpret_cast<const uint4*>(&Al[(size_t)r * K + c8 * 8]);
            } else {
                h = make_uint4(0u,0u,0u,0u);
                l = make_uint4(0u,0u,0u,0u);
            }
            *reinterpret_cast<uint4*>(&As_hi[row * PA + c8 * 8]) = h;
            *reinterpret_cast<uint4*>(&As_lo[row * PA + c8 * 8]) = l;
        }
        __syncthreads();

        f32x4 acc[4];
        #pragma unroll
        for (int nt = 0; nt < 4; nt++) { f32x4 z = {0.f,0.f,0.f,0.f}; acc[nt] = z; }
        #pragma unroll
        for (int chunk = 0; chunk < K / 32; chunk++) {
            short8_t ahi = *reinterpret_cast<const short8_t*>(
                &As_hi[(rbase + l16) * PA + chunk * 32 + quad * 8]);
            short8_t alo = *reinterpret_cast<const short8_t*>(
                &As_lo[(rbase + l16) * PA + chunk * 32 + quad * 8]);
            #pragma unroll
            for (int nt = 0; nt < 4; nt++) {
                short8_t bfr = *reinterpret_cast<const short8_t*>(
                    &Wt[((nbase + nt) * 16 + l16) * PA + chunk * 32 + quad * 8]);
                acc[nt] = __builtin_amdgcn_mfma_f32_16x16x32_bf16(alo, bfr, acc[nt], 0, 0, 0);
                acc[nt] = __builtin_amdgcn_mfma_f32_16x16x32_bf16(ahi, bfr, acc[nt], 0, 0, 0);
            }
        }
        const int rb = row0 + rbase + quad * 4;
        #pragma unroll
        for (int nt = 0; nt < 4; nt++) {
            #pragma unroll
            for (int rg = 0; rg < 4; rg++) {
                int r = rb + rg;
                if (r < N) {
                    float v = acc[nt][rg] + bcol[nt];
                    out[(size_t)r * 128 + (nbase + nt) * 16 + l16] = v;
                    csum[nt] += v; csq[nt] += v * v;
                }
            }
        }
    }
    #pragma unroll
    for (int nt = 0; nt < 4; nt++) {
        float s = csum[nt]; s += __shfl_xor(s, 16); s += __shfl_xor(s, 32);
        float q = csq[nt];  q += __shfl_xor(q, 16); q += __shfl_xor(q, 32);
        if (quad == 0) {
            int col = (nbase + nt) * 16 + l16;
            atomicAdd(&stats_out[col], s);
            atomicAdd(&stats_out[128 + col], q);
        }
    }
}

// ================================================================ MFMA GEMM with fused BN at staging
// out[N,128] = lrelu(bn(A)) @ W + bias, BN params from raw stats_in.
// In-place safe (out==A). Stats of out -> stats_out.
__global__ __launch_bounds__(256, 3) void gemm_bn_mfma_kernel(
    const float* __restrict__ A,
    const float* __restrict__ stats_in, const float* __restrict__ g,
    const float* __restrict__ be, float invN,
    const float* __restrict__ W, const float* __restrict__ bias,
    float* __restrict__ out, float* __restrict__ stats_out, int N, int ntiles)
{
    constexpr int K = 128;
    constexpr int PA = K + 8;
    __shared__ unsigned short As_hi[32 * PA];
    __shared__ unsigned short As_lo[32 * PA];
    __shared__ unsigned short Wt[128 * PA];
    __shared__ float scale_s[K];
    __shared__ float shift_s[K];
    const int tid = threadIdx.x;
    const int w = tid >> 6;
    const int lane = tid & 63;
    const int quad = lane >> 4;
    const int l16 = lane & 15;
    const int rbase = (w & 1) * 16;
    const int nbase = (w >> 1) * 4;

    for (int idx = tid; idx < K * 128; idx += 256) {
        int k = idx >> 7, nn = idx & 127;
        Wt[nn * PA + k] = f2bf(W[idx]);
    }
    for (int i = tid; i < K; i += 256) {
        float m = stats_in[i] * invN;
        float va = fmaxf(stats_in[K + i] * invN - m * m, 0.f);
        float sc = g[i] * rsqrtf(va + 1e-5f);
        scale_s[i] = sc;
        shift_s[i] = be[i] - m * sc;
    }
    float bcol[4];
    #pragma unroll
    for (int nt = 0; nt < 4; nt++) bcol[nt] = bias[(nbase + nt) * 16 + l16];
    float csum[4] = {0.f, 0.f, 0.f, 0.f}, csq[4] = {0.f, 0.f, 0.f, 0.f};

    constexpr int C8 = K / 8;

    for (int tile = blockIdx.x; tile < ntiles; tile += gridDim.x) {
        const int row0 = tile * 32;
        __syncthreads();
        for (int cid = tid; cid < 32 * C8; cid += 256) {
            int row = cid / C8, c8 = cid % C8;
            int r = row0 + row;
            float f[8];
            if (r < N) {
                float4 u0 = *reinterpret_cast<const float4*>(&A[(size_t)r * K + c8 * 8]);
                float4 u1 = *reinterpret_cast<const float4*>(&A[(size_t)r * K + c8 * 8 + 4]);
                f[0]=u0.x; f[1]=u0.y; f[2]=u0.z; f[3]=u0.w;
                f[4]=u1.x; f[5]=u1.y; f[6]=u1.z; f[7]=u1.w;
            } else {
                #pragma unroll
                for (int j = 0; j < 8; j++) f[j] = 0.f;
            }
            int kb = c8 * 8;
            #pragma unroll
            for (int j = 0; j < 8; j++)
                f[j] = lrelu(fmaf(f[j], scale_s[kb + j], shift_s[kb + j]));
            unsigned int hi[4], lo[4];
            #pragma unroll
            for (int j = 0; j < 4; j++) {
                unsigned int b0 = __float_as_uint(f[2*j]);
                unsigned int b1 = __float_as_uint(f[2*j + 1]);
                hi[j] = __builtin_amdgcn_perm(b1, b0, 0x07060302u);
                float l0 = f[2*j]     - __uint_as_float(b0 & 0xffff0000u);
                float l1 = f[2*j + 1] - __uint_as_float(b1 & 0xffff0000u);
                lo[j] = __builtin_amdgcn_perm(__float_as_uint(l1), __float_as_uint(l0), 0x07060302u);
            }
            *reinterpret_cast<uint4*>(&As_hi[row * PA + c8 * 8]) = make_uint4(hi[0], hi[1], hi[2], hi[3]);
            *reinterpret_cast<uint4*>(&As_lo[row * PA + c8 * 8]) = make_uint4(lo[0], lo[1], lo[2], lo[3]);
        }
        __syncthreads();

        f32x4 acc[4];
        #pragma unroll
        for (int nt = 0; nt < 4; nt++) { f32x4 z = {0.f,0.f,0.f,0.f}; acc[nt] = z; }
        #pragma unroll
        for (int chunk = 0; chunk < K / 32; chunk++) {
            short8_t ahi = *reinterpret_cast<const short8_t*>(
                &As_hi[(rbase + l16) * PA + chunk * 32 + quad * 8]);
            short8_t alo = *reinterpret_cast<const short8_t*>(
                &As_lo[(rbase + l16) * PA + chunk * 32 + quad * 8]);
            #pragma unroll
            for (int nt = 0; nt < 4; nt++) {
                short8_t bfr = *reinterpret_cast<const short8_t*>(
                    &Wt[((nbase + nt) * 16 + l16) * PA + chunk * 32 + quad * 8]);
                acc[nt] = __builtin_amdgcn_mfma_f32_16x16x32_bf16(alo, bfr, acc[nt], 0, 0, 0);
                acc[nt] = __builtin_amdgcn_mfma_f32_16x16x32_bf16(ahi, bfr, acc[nt], 0, 0, 0);
            }
        }
        const int rb = row0 + rbase + quad * 4;
        #pragma unroll
        for (int nt = 0; nt < 4; nt++) {
            #pragma unroll
            for (int rg = 0; rg < 4; rg++) {
                int r = rb + rg;
                if (r < N) {
                    float v = acc[nt][rg] + bcol[nt];
                    out[(size_t)r * 128 + (nbase + nt) * 16 + l16] = v;
                    csum[nt] += v; csq[nt] += v * v;
                }
            }
        }
    }
    #pragma unroll
    for (int nt = 0; nt < 4; nt++) {
        float s = csum[nt]; s += __shfl_xor(s, 16); s += __shfl_xor(s, 32);
        float q = csq[nt];  q += __shfl_xor(q, 16); q += __shfl_xor(q, 32);
        if (quad == 0) {
            int col = (nbase + nt) * 16 + l16;
            atomicAdd(&stats_out[col], s);
            atomicAdd(&stats_out[128 + col], q);
        }
    }
}

// ================================================================ global add pool (BN fused)
__global__ __launch_bounds__(256) void pool_kernel_bn(
    const float* __restrict__ U, const int* __restrict__ batch,
    const float* __restrict__ stats, const float* __restrict__ g,
    const float* __restrict__ be, float invN,
    float* __restrict__ pool, int N)
{
    int w = (blockIdx.x * 256 + threadIdx.x) >> 6;
    int lane = threadIdx.x & 63;
    int n0 = w * 32;
    if (n0 >= N) return;
    int n1 = min(n0 + 32, N);
    int c0 = lane * 2;
    float sc0, sh0, sc1, sh1;
    {
        float m0 = stats[c0] * invN;
        float v0 = fmaxf(stats[128 + c0] * invN - m0 * m0, 0.f);
        sc0 = g[c0] * rsqrtf(v0 + 1e-5f);
        sh0 = be[c0] - m0 * sc0;
        float m1 = stats[c0 + 1] * invN;
        float v1 = fmaxf(stats[128 + c0 + 1] * invN - m1 * m1, 0.f);
        sc1 = g[c0 + 1] * rsqrtf(v1 + 1e-5f);
        sh1 = be[c0 + 1] - m1 * sc1;
    }
    float a0 = 0.f, a1 = 0.f;
    int cur = batch[n0];
    for (int n = n0; n < n1; ++n) {
        int b = batch[n];
        if (b != cur) {
            atomicAdd(&pool[(size_t)cur * 128 + c0], a0);
            atomicAdd(&pool[(size_t)cur * 128 + c0 + 1], a1);
            a0 = a1 = 0.f; cur = b;
        }
        float2 v = *reinterpret_cast<const float2*>(&U[(size_t)n * 128 + c0]);
        a0 += lrelu(fmaf(v.x, sc0, sh0));
        a1 += lrelu(fmaf(v.y, sc1, sh1));
    }
    atomicAdd(&pool[(size_t)cur * 128 + c0], a0);
    atomicAdd(&pool[(size_t)cur * 128 + c0 + 1], a1);
}

// ================================================================ final (BN fused)
__global__ __launch_bounds__(256) void final_kernel_bn(
    const float* __restrict__ U, const float* __restrict__ pool,
    const int* __restrict__ batch,
    const float* __restrict__ stats, const float* __restrict__ g,
    const float* __restrict__ be, float invN,
    const float* __restrict__ wf, const float* __restrict__ bf,
    float* __restrict__ out, int N)
{
    __shared__ float wf_s[512];
    int tid = threadIdx.x;
    for (int i = tid; i < 512; i += 256) wf_s[i] = wf[i];
    __syncthreads();
    int wid = tid >> 6, lane = tid & 63;
    int n = blockIdx.x * 4 + wid;
    if (n >= N) return;
    int cA = lane, cB = 64 + lane;
    float scA, shA, scB, shB;
    {
        float mA = stats[cA] * invN;
        float vA = fmaxf(stats[128 + cA] * invN - mA * mA, 0.f);
        scA = g[cA] * rsqrtf(vA + 1e-5f);
        shA = be[cA] - mA * scA;
        float mB = stats[cB] * invN;
        float vB = fmaxf(stats[128 + cB] * invN - mB * mB, 0.f);
        scB = g[cB] * rsqrtf(vB + 1e-5f);
        shB = be[cB] - mB * scB;
    }
    int b = batch[n];
    float v0 = lrelu(fmaf(U[(size_t)n * 128 + cA], scA, shA));
    float v1 = lrelu(fmaf(U[(size_t)n * 128 + cB], scB, shB));
    float p0 = pool[(size_t)b * 128 + cA];
    float p1 = pool[(size_t)b * 128 + cB];
    float a0 = v0 * wf_s[lane * 2]       + v1 * wf_s[(64 + lane) * 2]
             + p0 * wf_s[(128 + lane) * 2] + p1 * wf_s[(192 + lane) * 2];
    float a1 = v0 * wf_s[lane * 2 + 1]       + v1 * wf_s[(64 + lane) * 2 + 1]
             + p0 * wf_s[(128 + lane) * 2 + 1] + p1 * wf_s[(192 + lane) * 2 + 1];
    #pragma unroll
    for (int off = 32; off >= 1; off >>= 1) {
        a0 += __shfl_down(a0, off);
        a1 += __shfl_down(a1, off);
    }
    if (lane == 0) {
        a0 += bf[0]; a1 += bf[1];
        float mx = fmaxf(a0, a1);
        float e0 = __expf(a0 - mx), e1 = __expf(a1 - mx);
        float inv = 1.f / (e0 + e1);
        out[(size_t)n * 2]     = e0 * inv;
        out[(size_t)n * 2 + 1] = e1 * inv;
    }
}

// ================================================================ launch
extern "C" void kernel_launch(void* const* d_in, const int* in_sizes, int n_in,
                              void* d_out, int out_size, void* d_ws, size_t ws_size,
                              hipStream_t stream)
{
    const float* x0    = (const float*)d_in[0];
    const int*   ei    = (const int*)d_in[1];
    const float* ea    = (const float*)d_in[2];
    const int*   batch = (const int*)d_in[3];
    const int E = in_sizes[1] / 2;
    const int N = in_sizes[3];
    const int* srcv = ei;
    const int* dstv = ei + E;
    const float* wf = (const float*)d_in[37];
    const float* bfp = (const float*)d_in[38];
    float* out = (float*)d_out;
    const float invN = 1.0f / (float)N;
    const int ntiles = (N + 31) / 32;

    // ---- workspace layout (floats) ----
    const size_t base_f = (size_t)2 * N * 128 + (size_t)GNUM * 128 + 6 * 256
                        + (size_t)(N + 1) + (size_t)N + 128 + (size_t)E;
    const size_t full_f = base_f + (size_t)E * 16 + (size_t)E;
    const bool ro = (ws_size >= full_f * 4);

    float* ws = (float*)d_ws;
    size_t o = 0;
    float* xA    = ws + o; o += (size_t)N * 128;   // U buffer (fp32)
    float* xB    = ws + o; o += (size_t)N * 128;   // hi/lo plane space
    float* eap   = ws + o; o += ro ? (size_t)E * 16 : 0;
    float* poolb = ws + o; o += (size_t)GNUM * 128;
    float* statsb= ws + o; o += 6 * 256;
    int* srcp    = (int*)(ws + o); o += ro ? (size_t)E : 0;
    int* off     = (int*)(ws + o); o += (size_t)(N + 1);
    int* cursor  = (int*)(ws + o); o += (size_t)N;
    int* bsumb   = (int*)(ws + o); o += 128;
    int* perm    = (int*)(ws + o);

    // hi/lo bf16 planes live inside xB
    unsigned short* planeh = (unsigned short*)xB;

    // ---- CSR build (by destination) ----
    hipMemsetAsync(off, 0, (size_t)(N + 1) * sizeof(int), stream);
    hipMemsetAsync(statsb, 0, (size_t)6 * 256 * sizeof(float), stream);
    hipMemsetAsync(poolb, 0, (size_t)GNUM * 128 * sizeof(float), stream);
    hist_kernel<<<(E + 255) / 256, 256, 0, stream>>>(dstv, off, E);
    const int n1 = N + 1;
    const int nb = (n1 + 1023) / 1024;
    scan_block_kernel<<<nb, 256, 0, stream>>>(off, bsumb, n1);
    scan_carry_kernel<<<1, 128, 0, stream>>>(bsumb, nb);
    scan_add_kernel<<<(n1 + 255) / 256, 256, 0, stream>>>(off, bsumb, cursor, n1, N);
    scatter_kernel<<<(E + 255) / 256, 256, 0, stream>>>(dstv, cursor, perm, E);
    if (ro)
        reorder_kernel<<<(E * 4 + 255) / 256, 256, 0, stream>>>(ea, srcv, perm, eap, srcp, E);

    const float* g_ea  = ro ? eap  : ea;
    const int*   g_src = ro ? srcp : srcv;
    const int gather_blocks = (N + 3) / 4;

    const float *pg = nullptr, *pbe = nullptr;
    float* pstats = nullptr;

    for (int l = 0; l < 3; l++) {
        const int C = (l == 0) ? 32 : 128;
        int bidx = 4 + l * 11;
        const float* epsp = (const float*)d_in[bidx + 0];
        const float* ew   = (const float*)d_in[bidx + 1];
        const float* eb   = (const float*)d_in[bidx + 2];
        const float* w1   = (const float*)d_in[bidx + 3];
        const float* b1   = (const float*)d_in[bidx + 4];
        const float* g1   = (const float*)d_in[bidx + 5];
        const float* be1  = (const float*)d_in[bidx + 6];
        const float* w2   = (const float*)d_in[bidx + 7];
        const float* b2   = (const float*)d_in[bidx + 8];
        const float* g2   = (const float*)d_in[bidx + 9];
        const float* be2  = (const float*)d_in[bidx + 10];
        float* st1 = statsb + (size_t)(l * 2) * 256;
        float* st2 = statsb + (size_t)(l * 2 + 1) * 256;

        unsigned short* ah = planeh;                     // hi plane [N*C]
        unsigned short* al = planeh + (size_t)N * C;     // lo plane [N*C]

        if (l == 0) {
            if (ro) gather_kernel32<true><<<gather_blocks, 256, 0, stream>>>(
                        g_ea, g_src, perm, off, ew, eb, epsp, x0, ah, al, N);
            else    gather_kernel32<false><<<gather_blocks, 256, 0, stream>>>(
                        g_ea, g_src, perm, off, ew, eb, epsp, x0, ah, al, N);
            gemm_copy_mfma_kernel<32><<<GEMM_GRID, 256, 0, stream>>>(
                ah, al, w1, b1, xA, st1, N, ntiles);
        } else {
            if (ro) gather_kernel128_bn<true><<<gather_blocks, 256, 0, stream>>>(
                        g_ea, g_src, perm, off, ew, eb, epsp, xA,
                        pstats, pg, pbe, invN, ah, al, N);
            else    gather_kernel128_bn<false><<<gather_blocks, 256, 0, stream>>>(
                        g_ea, g_src, perm, off, ew, eb, epsp, xA,
                        pstats, pg, pbe, invN, ah, al, N);
            gemm_copy_mfma_kernel<128><<<GEMM_GRID, 256, 0, stream>>>(
                ah, al, w1, b1, xA, st1, N, ntiles);
        }
        gemm_bn_mfma_kernel<<<GEMM_GRID, 256, 0, stream>>>(
            xA, st1, g1, be1, invN, w2, b2, xA, st2, N, ntiles);
        pstats = st2; pg = g2; pbe = be2;
    }
    pool_kernel_bn<<<((N + 31) / 32 * 64 + 255) / 256, 256, 0, stream>>>(
        xA, batch, pstats, pg, pbe, invN, poolb, N);
    final_kernel_bn<<<(N + 3) / 4, 256, 0, stream>>>(
        xA, poolb, batch, pstats, pg, pbe, invN, wf, bfp, out, N);
}